// Round 2
// baseline (1003.744 us; speedup 1.0000x reference)
//
#include <hip/hip_runtime.h>

#define NN 50000
#define EE 800000
#define INC 128
#define HCC 128
#define RR 8
#define HH 4

// ---------- helpers ----------
static __device__ __forceinline__ unsigned f2b_rne(float f) {
    unsigned u = __float_as_uint(f);
    return (u + 0x7FFFu + ((u >> 16) & 1u)) >> 16;
}
static __device__ __forceinline__ float b2f(unsigned short s) {
    return __uint_as_float(((unsigned)s) << 16);
}
// order-preserving float->uint map for atomicMax
static __device__ __forceinline__ unsigned fmap(float f) {
    unsigned u = __float_as_uint(f);
    return (u & 0x80000000u) ? ~u : (u | 0x80000000u);
}
static __device__ __forceinline__ float funmap(unsigned u) {
    unsigned b = (u & 0x80000000u) ? (u ^ 0x80000000u) : ~u;
    return __uint_as_float(b);
}

// ---------- K0: Wq[r,i,h] = sum_o W[r,i,o]*q[o,h]; same for k ----------
__global__ __launch_bounds__(128) void k_wqk(const float* __restrict__ W,
                                             const float* __restrict__ qw,
                                             const float* __restrict__ kw,
                                             float* __restrict__ Wq,
                                             float* __restrict__ Wk) {
    int r = blockIdx.x, i = threadIdx.x;
    const float* wrow = W + (r * INC + i) * HCC;
    float aq0 = 0, aq1 = 0, aq2 = 0, aq3 = 0;
    float ak0 = 0, ak1 = 0, ak2 = 0, ak3 = 0;
    for (int o = 0; o < HCC; ++o) {
        float w = wrow[o];
        float4 qv = *(const float4*)(qw + o * 4);
        float4 kv = *(const float4*)(kw + o * 4);
        aq0 = fmaf(w, qv.x, aq0); aq1 = fmaf(w, qv.y, aq1);
        aq2 = fmaf(w, qv.z, aq2); aq3 = fmaf(w, qv.w, aq3);
        ak0 = fmaf(w, kv.x, ak0); ak1 = fmaf(w, kv.y, ak1);
        ak2 = fmaf(w, kv.z, ak2); ak3 = fmaf(w, kv.w, ak3);
    }
    *(float4*)(Wq + (r * INC + i) * 4) = make_float4(aq0, aq1, aq2, aq3);
    *(float4*)(Wk + (r * INC + i) * 4) = make_float4(ak0, ak1, ak2, ak3);
}

// ---------- K1: QT[n,r,h] = x[n,:]·Wq[r,:,h]; KT likewise ----------
__global__ __launch_bounds__(256) void k_qtkt(const float* __restrict__ x,
                                              const float* __restrict__ Wq,
                                              const float* __restrict__ Wk,
                                              float* __restrict__ QT,
                                              float* __restrict__ KT) {
    int pair = blockIdx.x * 256 + threadIdx.x;
    if (pair >= NN * RR) return;
    int n = pair >> 3, r = pair & 7;
    const float* xr = x + n * INC;
    const float* wq = Wq + r * INC * 4;
    const float* wk = Wk + r * INC * 4;
    float aq0 = 0, aq1 = 0, aq2 = 0, aq3 = 0;
    float ak0 = 0, ak1 = 0, ak2 = 0, ak3 = 0;
    for (int i = 0; i < INC; ++i) {
        float xv = xr[i];
        float4 qv = *(const float4*)(wq + i * 4);
        float4 kv = *(const float4*)(wk + i * 4);
        aq0 = fmaf(xv, qv.x, aq0); aq1 = fmaf(xv, qv.y, aq1);
        aq2 = fmaf(xv, qv.z, aq2); aq3 = fmaf(xv, qv.w, aq3);
        ak0 = fmaf(xv, kv.x, ak0); ak1 = fmaf(xv, kv.y, ak1);
        ak2 = fmaf(xv, kv.z, ak2); ak3 = fmaf(xv, kv.w, ak3);
    }
    *(float4*)(QT + pair * 4) = make_float4(aq0, aq1, aq2, aq3);
    *(float4*)(KT + pair * 4) = make_float4(ak0, ak1, ak2, ak3);
}

// ---------- K2: T[n,r,:] = x[n,:] @ W_r   (fp32 vector, bf16 out) ----------
__global__ __launch_bounds__(256) void k_T(const float* __restrict__ x,
                                           const float* __restrict__ W,
                                           unsigned short* __restrict__ T) {
    __shared__ float xs[64 * 129];  // 64 nodes x 128 k, pad 1 (2-way bank alias = free)
    const int tid = threadIdx.x;
    const int n0 = blockIdx.x * 64;
#pragma unroll
    for (int it = 0; it < 8; ++it) {
        int flat = it * 1024 + tid * 4;
        int n = flat >> 7, kk = flat & 127;
        int gn = n0 + n; gn = gn < NN ? gn : NN - 1;
        float4 v = *(const float4*)(x + gn * 128 + kk);
        float* d = xs + n * 129 + kk;  // scalar writes: 129-stride not 16B aligned
        d[0] = v.x; d[1] = v.y; d[2] = v.z; d[3] = v.w;
    }
    __syncthreads();
    const int ng = tid >> 4;        // 0..15 -> node group of 4
    const int ob = (tid & 15) * 8;  // 8 consecutive outputs
    for (int r = 0; r < RR; ++r) {
        float acc[4][8];
#pragma unroll
        for (int i = 0; i < 4; ++i)
#pragma unroll
            for (int jj = 0; jj < 8; ++jj) acc[i][jj] = 0.f;
        const float* Wr = W + r * INC * HCC;
#pragma unroll 4
        for (int k = 0; k < INC; ++k) {
            float4 w0 = *(const float4*)(Wr + k * HCC + ob);
            float4 w1 = *(const float4*)(Wr + k * HCC + ob + 4);
#pragma unroll
            for (int i = 0; i < 4; ++i) {
                float xv = xs[(ng * 4 + i) * 129 + k];
                acc[i][0] = fmaf(xv, w0.x, acc[i][0]);
                acc[i][1] = fmaf(xv, w0.y, acc[i][1]);
                acc[i][2] = fmaf(xv, w0.z, acc[i][2]);
                acc[i][3] = fmaf(xv, w0.w, acc[i][3]);
                acc[i][4] = fmaf(xv, w1.x, acc[i][4]);
                acc[i][5] = fmaf(xv, w1.y, acc[i][5]);
                acc[i][6] = fmaf(xv, w1.z, acc[i][6]);
                acc[i][7] = fmaf(xv, w1.w, acc[i][7]);
            }
        }
#pragma unroll
        for (int i = 0; i < 4; ++i) {
            int gn = n0 + ng * 4 + i;
            if (gn >= NN) continue;
            uint4 pk;
            pk.x = f2b_rne(acc[i][0]) | (f2b_rne(acc[i][1]) << 16);
            pk.y = f2b_rne(acc[i][2]) | (f2b_rne(acc[i][3]) << 16);
            pk.z = f2b_rne(acc[i][4]) | (f2b_rne(acc[i][5]) << 16);
            pk.w = f2b_rne(acc[i][6]) | (f2b_rne(acc[i][7]) << 16);
            *(uint4*)(T + (gn * RR + r) * HCC + ob) = pk;
        }
    }
}

// ---------- CSR build ----------
__global__ __launch_bounds__(256) void k_hist(const int* __restrict__ ei,
                                              int* __restrict__ deg) {
    int e = blockIdx.x * 256 + threadIdx.x;
    if (e >= EE) return;
    atomicAdd(&deg[ei[EE + e]], 1);
}

__global__ __launch_bounds__(1024) void k_scan1(const int* __restrict__ deg,
                                                int* __restrict__ rowptr,
                                                int* __restrict__ bsum) {
    __shared__ int s[1024];
    int tid = threadIdx.x;
    int g = blockIdx.x * 1024 + tid;
    int v = (g < NN) ? deg[g] : 0;
    s[tid] = v;
    __syncthreads();
    for (int off = 1; off < 1024; off <<= 1) {
        int t = (tid >= off) ? s[tid - off] : 0;
        __syncthreads();
        s[tid] += t;
        __syncthreads();
    }
    if (g < NN) rowptr[g + 1] = s[tid];  // chunk-local inclusive
    if (tid == 1023) bsum[blockIdx.x] = s[1023];
}

__global__ void k_scan2(const int* __restrict__ bsum, int* __restrict__ boff) {
    int tid = threadIdx.x;  // 64 = 1 wave
    const int NB = (NN + 1023) / 1024;  // 49
    int v = (tid < NB) ? bsum[tid] : 0;
    int orig = v;
    for (int off = 1; off < 64; off <<= 1) {
        int t = __shfl_up(v, off);
        if (tid >= off) v += t;
    }
    if (tid < NB) boff[tid] = v - orig;  // exclusive
}

__global__ __launch_bounds__(1024) void k_scan3(int* __restrict__ rowptr,
                                                const int* __restrict__ boff) {
    int tid = threadIdx.x;
    int g = blockIdx.x * 1024 + tid;
    if (g == 0) rowptr[0] = 0;
    if (g < NN) rowptr[g + 1] += boff[blockIdx.x];
}

__global__ __launch_bounds__(256) void k_scatter(const int* __restrict__ ei,
                                                 const int* __restrict__ et,
                                                 const int* __restrict__ rowptr,
                                                 int* __restrict__ cursor,
                                                 unsigned* __restrict__ srow,
                                                 int* __restrict__ slot) {
    int e = blockIdx.x * 256 + threadIdx.x;
    if (e >= EE) return;
    int src = ei[e], dst = ei[EE + e], r = et[e];
    int pos = rowptr[dst] + atomicAdd(&cursor[dst], 1);
    srow[pos] = (unsigned)(src * RR + r);  // T row index
    slot[e] = pos;
}

// ---------- attention logits + segment max ----------
__global__ __launch_bounds__(256) void k_alpha(const int* __restrict__ ei,
                                               const int* __restrict__ et,
                                               const float* __restrict__ QT,
                                               const float* __restrict__ KT,
                                               float* __restrict__ alpha,
                                               unsigned* __restrict__ amaxU) {
    int e = blockIdx.x * 256 + threadIdx.x;
    if (e >= EE) return;
    int src = ei[e], dst = ei[EE + e], r = et[e];
    float4 qi = *(const float4*)(QT + (dst * RR + r) * 4);
    float4 kj = *(const float4*)(KT + (src * RR + r) * 4);
    float a0 = qi.x + kj.x, a1 = qi.y + kj.y, a2 = qi.z + kj.z, a3 = qi.w + kj.w;
    a0 = a0 > 0.f ? a0 : 0.2f * a0;
    a1 = a1 > 0.f ? a1 : 0.2f * a1;
    a2 = a2 > 0.f ? a2 : 0.2f * a2;
    a3 = a3 > 0.f ? a3 : 0.2f * a3;
    *(float4*)(alpha + e * 4) = make_float4(a0, a1, a2, a3);
    atomicMax(&amaxU[dst * 4 + 0], fmap(a0));
    atomicMax(&amaxU[dst * 4 + 1], fmap(a1));
    atomicMax(&amaxU[dst * 4 + 2], fmap(a2));
    atomicMax(&amaxU[dst * 4 + 3], fmap(a3));
}

// ---------- exp + segment sum; scatter ex to sorted slot ----------
__global__ __launch_bounds__(256) void k_exp(const int* __restrict__ ei,
                                             const float* __restrict__ alpha,
                                             const unsigned* __restrict__ amaxU,
                                             const int* __restrict__ slot,
                                             float* __restrict__ exs,
                                             float* __restrict__ denom) {
    int e = blockIdx.x * 256 + threadIdx.x;
    if (e >= EE) return;
    int dst = ei[EE + e];
    float4 a = *(const float4*)(alpha + e * 4);
    uint4 mu = *(const uint4*)(amaxU + dst * 4);
    float e0 = expf(a.x - funmap(mu.x));
    float e1 = expf(a.y - funmap(mu.y));
    float e2 = expf(a.z - funmap(mu.z));
    float e3 = expf(a.w - funmap(mu.w));
    int pos = slot[e];
    *(float4*)(exs + pos * 4) = make_float4(e0, e1, e2, e3);
    atomicAdd(&denom[dst * 4 + 0], e0);
    atomicAdd(&denom[dst * 4 + 1], e1);
    atomicAdd(&denom[dst * 4 + 2], e2);
    atomicAdd(&denom[dst * 4 + 3], e3);
}

// ---------- per-node gather-aggregate ----------
__global__ __launch_bounds__(128) void k_agg(const int* __restrict__ rowptr,
                                             const unsigned* __restrict__ srow,
                                             const float* __restrict__ exs,
                                             const float* __restrict__ denom,
                                             const unsigned short* __restrict__ T,
                                             const float* __restrict__ bias,
                                             float* __restrict__ out) {
    int n = blockIdx.x;
    int c = threadIdx.x;
    int h = c >> 5;
    int beg = rowptr[n], end = rowptr[n + 1];
    float acc = 0.f;
    int j = beg;
    for (; j + 4 <= end; j += 4) {
        unsigned r0 = srow[j], r1 = srow[j + 1], r2 = srow[j + 2], r3 = srow[j + 3];
        float w0 = exs[j * 4 + h], w1 = exs[(j + 1) * 4 + h];
        float w2 = exs[(j + 2) * 4 + h], w3 = exs[(j + 3) * 4 + h];
        float t0 = b2f(T[r0 * HCC + c]), t1 = b2f(T[r1 * HCC + c]);
        float t2 = b2f(T[r2 * HCC + c]), t3 = b2f(T[r3 * HCC + c]);
        acc += w0 * t0 + w1 * t1 + w2 * t2 + w3 * t3;
    }
    for (; j < end; ++j) acc += exs[j * 4 + h] * b2f(T[srow[j] * HCC + c]);
    float d = denom[n * 4 + h];
    out[n * HCC + c] = acc / (d + 1e-16f) + bias[c];
}

extern "C" void kernel_launch(void* const* d_in, const int* in_sizes, int n_in,
                              void* d_out, int out_size, void* d_ws, size_t ws_size,
                              hipStream_t stream) {
    const float* x    = (const float*)d_in[0];
    const int*   ei   = (const int*)d_in[1];
    const int*   et   = (const int*)d_in[2];
    const float* W    = (const float*)d_in[3];
    const float* qw   = (const float*)d_in[4];
    const float* kw   = (const float*)d_in[5];
    const float* bias = (const float*)d_in[6];
    float* out = (float*)d_out;
    char* ws = (char*)d_ws;

    // workspace layout (bytes) — total ~149.4 MB
    unsigned short* T  = (unsigned short*)(ws + 0);          // 102,400,000
    float* QT          = (float*)(ws + 102400000);           //   6,400,000
    float* KT          = (float*)(ws + 108800000);           //   6,400,000
    float* alpha       = (float*)(ws + 115200000);           //  12,800,000
    float* exs         = (float*)(ws + 128000000);           //  12,800,000
    float* Wq          = (float*)(ws + 140800000);           //      16,384
    float* Wk          = (float*)(ws + 140816384);           //      16,384
    unsigned* amaxU    = (unsigned*)(ws + 140832768);        //     800,000  (zeroed)
    float* denom       = (float*)(ws + 141632768);           //     800,000  (zeroed)
    int* deg           = (int*)(ws + 142432768);             //     200,000  (zeroed)
    int* cursor        = (int*)(ws + 142632768);             //     200,000  (zeroed)
    int* rowptr        = (int*)(ws + 142832768);             //     200,004
    int* bsum          = (int*)(ws + 143032960);             //         256
    int* boff          = (int*)(ws + 143033216);             //         256
    unsigned* srow     = (unsigned*)(ws + 143033472);        //   3,200,000
    int* slot          = (int*)(ws + 146233472);             //   3,200,000

    hipMemsetAsync(ws + 140832768, 0, 2000000, stream);  // amaxU|denom|deg|cursor

    k_wqk<<<RR, 128, 0, stream>>>(W, qw, kw, Wq, Wk);
    k_qtkt<<<(NN * RR + 255) / 256, 256, 0, stream>>>(x, Wq, Wk, QT, KT);
    k_T<<<(NN + 63) / 64, 256, 0, stream>>>(x, W, T);
    k_hist<<<(EE + 255) / 256, 256, 0, stream>>>(ei, deg);
    k_scan1<<<49, 1024, 0, stream>>>(deg, rowptr, bsum);
    k_scan2<<<1, 64, 0, stream>>>(bsum, boff);
    k_scan3<<<49, 1024, 0, stream>>>(rowptr, boff);
    k_scatter<<<(EE + 255) / 256, 256, 0, stream>>>(ei, et, rowptr, cursor, srow, slot);
    k_alpha<<<(EE + 255) / 256, 256, 0, stream>>>(ei, et, QT, KT, alpha, amaxU);
    k_exp<<<(EE + 255) / 256, 256, 0, stream>>>(ei, alpha, amaxU, slot, exs, denom);
    k_agg<<<NN, 128, 0, stream>>>(rowptr, srow, exs, denom, T, bias, out);
}

// Round 3
// 808.190 us; speedup vs baseline: 1.2420x; 1.2420x over previous
//
#include <hip/hip_runtime.h>

#define NN 50000
#define EE 800000
#define INC 128
#define HCC 128
#define RR 8
#define HH 4

typedef __attribute__((ext_vector_type(8))) short bf16x8;
typedef __attribute__((ext_vector_type(4))) float f32x4;

// ---------- helpers ----------
static __device__ __forceinline__ unsigned f2b_rne(float f) {
    unsigned u = __float_as_uint(f);
    return (u + 0x7FFFu + ((u >> 16) & 1u)) >> 16;
}
static __device__ __forceinline__ float b2f(unsigned short s) {
    return __uint_as_float(((unsigned)s) << 16);
}
// order-preserving float->uint map for atomicMax
static __device__ __forceinline__ unsigned fmap(float f) {
    unsigned u = __float_as_uint(f);
    return (u & 0x80000000u) ? ~u : (u | 0x80000000u);
}
static __device__ __forceinline__ float funmap(unsigned u) {
    unsigned b = (u & 0x80000000u) ? (u ^ 0x80000000u) : ~u;
    return __uint_as_float(b);
}

// ---------- prologue: x fp32 -> bf16 (row-major, feeds MFMA B-fragments) ----------
__global__ __launch_bounds__(256) void k_cvt_x(const float* __restrict__ x,
                                               unsigned short* __restrict__ xb) {
    int t = blockIdx.x * 256 + threadIdx.x;  // 800000 threads, 8 elems each
    const float4* p = (const float4*)x + t * 2;
    float4 v0 = p[0], v1 = p[1];
    uint4 pk;
    pk.x = f2b_rne(v0.x) | (f2b_rne(v0.y) << 16);
    pk.y = f2b_rne(v0.z) | (f2b_rne(v0.w) << 16);
    pk.z = f2b_rne(v1.x) | (f2b_rne(v1.y) << 16);
    pk.w = f2b_rne(v1.z) | (f2b_rne(v1.w) << 16);
    *((uint4*)xb + t) = pk;
}

// ---------- prologue: Wt[r][o][i] = bf16(W[r][i][o])  (A-fragment layout) ----------
__global__ __launch_bounds__(256) void k_cvt_wt(const float* __restrict__ W,
                                                unsigned short* __restrict__ Wt) {
    int t = blockIdx.x * 256 + threadIdx.x;  // 16384 threads
    int m = t & 127, kb = (t >> 7) & 15, r = t >> 11;
    unsigned short tmp[8];
#pragma unroll
    for (int j = 0; j < 8; ++j)
        tmp[j] = (unsigned short)f2b_rne(W[((r << 7) + (kb << 3) + j) * 128 + m]);
    uint4 pk;
    pk.x = tmp[0] | ((unsigned)tmp[1] << 16);
    pk.y = tmp[2] | ((unsigned)tmp[3] << 16);
    pk.z = tmp[4] | ((unsigned)tmp[5] << 16);
    pk.w = tmp[6] | ((unsigned)tmp[7] << 16);
    *(uint4*)(Wt + ((r << 7) + m) * 128 + (kb << 3)) = pk;
}

// ---------- K0: Wq[r,i,h] = sum_o W[r,i,o]*q[o,h]; same for k ----------
__global__ __launch_bounds__(128) void k_wqk(const float* __restrict__ W,
                                             const float* __restrict__ qw,
                                             const float* __restrict__ kw,
                                             float* __restrict__ Wq,
                                             float* __restrict__ Wk) {
    int r = blockIdx.x, i = threadIdx.x;
    const float* wrow = W + (r * INC + i) * HCC;
    float aq0 = 0, aq1 = 0, aq2 = 0, aq3 = 0;
    float ak0 = 0, ak1 = 0, ak2 = 0, ak3 = 0;
    for (int o = 0; o < HCC; ++o) {
        float w = wrow[o];
        float4 qv = *(const float4*)(qw + o * 4);
        float4 kv = *(const float4*)(kw + o * 4);
        aq0 = fmaf(w, qv.x, aq0); aq1 = fmaf(w, qv.y, aq1);
        aq2 = fmaf(w, qv.z, aq2); aq3 = fmaf(w, qv.w, aq3);
        ak0 = fmaf(w, kv.x, ak0); ak1 = fmaf(w, kv.y, ak1);
        ak2 = fmaf(w, kv.z, ak2); ak3 = fmaf(w, kv.w, ak3);
    }
    *(float4*)(Wq + (r * INC + i) * 4) = make_float4(aq0, aq1, aq2, aq3);
    *(float4*)(Wk + (r * INC + i) * 4) = make_float4(ak0, ak1, ak2, ak3);
}

// ---------- K1: QT[n,r,h] = x[n,:]·Wq[r,:,h]; KT likewise ----------
__global__ __launch_bounds__(256) void k_qtkt(const float* __restrict__ x,
                                              const float* __restrict__ Wq,
                                              const float* __restrict__ Wk,
                                              float* __restrict__ QT,
                                              float* __restrict__ KT) {
    int pair = blockIdx.x * 256 + threadIdx.x;
    if (pair >= NN * RR) return;
    int n = pair >> 3, r = pair & 7;
    const float* xr = x + n * INC;
    const float* wq = Wq + r * INC * 4;
    const float* wk = Wk + r * INC * 4;
    float aq0 = 0, aq1 = 0, aq2 = 0, aq3 = 0;
    float ak0 = 0, ak1 = 0, ak2 = 0, ak3 = 0;
    for (int i = 0; i < INC; ++i) {
        float xv = xr[i];
        float4 qv = *(const float4*)(wq + i * 4);
        float4 kv = *(const float4*)(wk + i * 4);
        aq0 = fmaf(xv, qv.x, aq0); aq1 = fmaf(xv, qv.y, aq1);
        aq2 = fmaf(xv, qv.z, aq2); aq3 = fmaf(xv, qv.w, aq3);
        ak0 = fmaf(xv, kv.x, ak0); ak1 = fmaf(xv, kv.y, ak1);
        ak2 = fmaf(xv, kv.z, ak2); ak3 = fmaf(xv, kv.w, ak3);
    }
    *(float4*)(QT + pair * 4) = make_float4(aq0, aq1, aq2, aq3);
    *(float4*)(KT + pair * 4) = make_float4(ak0, ak1, ak2, ak3);
}

// ---------- K2 (MFMA): T[n,r,:] = x[n,:] @ W_r, computed transposed ----------
// A = Wt_r (M=128 out-chan, K=128), B = x-tile (N=16 nodes), D lane: node=lane&15,
// chan=(lane>>4)*4+reg -> 4 consecutive channels per lane -> 8B packed bf16 store.
// Each wave: 2 node-tiles (32 nodes) x full 128 chans, 64 MFMA.
__global__ __launch_bounds__(256) void k_T(const unsigned short* __restrict__ xb,
                                           const unsigned short* __restrict__ Wt,
                                           unsigned short* __restrict__ T) {
    int wave = (blockIdx.x * 256 + threadIdx.x) >> 6;  // 0..12503
    int lane = threadIdx.x & 63;
    int r = wave & 7;
    int p = wave >> 3;          // 0..1562
    int nt0 = p * 2, nt1 = nt0 + 1;
    bool has1 = nt1 < 3125;
    int ln = lane & 15, kq = lane >> 4;

    const unsigned short* x0 = xb + (nt0 * 16 + ln) * 128 + kq * 8;
    const unsigned short* x1 = xb + ((has1 ? nt1 : nt0) * 16 + ln) * 128 + kq * 8;
    bf16x8 b0[4], b1[4];
#pragma unroll
    for (int ks = 0; ks < 4; ++ks) {
        b0[ks] = *(const bf16x8*)(x0 + ks * 32);
        b1[ks] = *(const bf16x8*)(x1 + ks * 32);
    }
    const unsigned short* wb = Wt + (r * 128 + ln) * 128 + kq * 8;
#pragma unroll
    for (int mg = 0; mg < 8; ++mg) {
        f32x4 acc0 = {0.f, 0.f, 0.f, 0.f};
        f32x4 acc1 = {0.f, 0.f, 0.f, 0.f};
#pragma unroll
        for (int ks = 0; ks < 4; ++ks) {
            bf16x8 a = *(const bf16x8*)(wb + mg * 2048 + ks * 32);
            acc0 = __builtin_amdgcn_mfma_f32_16x16x32_bf16(a, b0[ks], acc0, 0, 0, 0);
            acc1 = __builtin_amdgcn_mfma_f32_16x16x32_bf16(a, b1[ks], acc1, 0, 0, 0);
        }
        uint2 pk0, pk1;
        pk0.x = f2b_rne(acc0[0]) | (f2b_rne(acc0[1]) << 16);
        pk0.y = f2b_rne(acc0[2]) | (f2b_rne(acc0[3]) << 16);
        pk1.x = f2b_rne(acc1[0]) | (f2b_rne(acc1[1]) << 16);
        pk1.y = f2b_rne(acc1[2]) | (f2b_rne(acc1[3]) << 16);
        int c = mg * 16 + kq * 4;
        *(uint2*)(T + ((nt0 * 16 + ln) * 8 + r) * 128 + c) = pk0;
        if (has1) *(uint2*)(T + ((nt1 * 16 + ln) * 8 + r) * 128 + c) = pk1;
    }
}

// ---------- CSR build ----------
__global__ __launch_bounds__(256) void k_hist(const int* __restrict__ ei,
                                              int* __restrict__ deg) {
    int e = blockIdx.x * 256 + threadIdx.x;
    if (e >= EE) return;
    atomicAdd(&deg[ei[EE + e]], 1);
}

__global__ __launch_bounds__(1024) void k_scan1(const int* __restrict__ deg,
                                                int* __restrict__ rowptr,
                                                int* __restrict__ bsum) {
    __shared__ int s[1024];
    int tid = threadIdx.x;
    int g = blockIdx.x * 1024 + tid;
    int v = (g < NN) ? deg[g] : 0;
    s[tid] = v;
    __syncthreads();
    for (int off = 1; off < 1024; off <<= 1) {
        int t = (tid >= off) ? s[tid - off] : 0;
        __syncthreads();
        s[tid] += t;
        __syncthreads();
    }
    if (g < NN) rowptr[g + 1] = s[tid];  // chunk-local inclusive
    if (tid == 1023) bsum[blockIdx.x] = s[1023];
}

__global__ void k_scan2(const int* __restrict__ bsum, int* __restrict__ boff) {
    int tid = threadIdx.x;  // 64 = 1 wave
    const int NB = (NN + 1023) / 1024;  // 49
    int v = (tid < NB) ? bsum[tid] : 0;
    int orig = v;
    for (int off = 1; off < 64; off <<= 1) {
        int t = __shfl_up(v, off);
        if (tid >= off) v += t;
    }
    if (tid < NB) boff[tid] = v - orig;  // exclusive
}

__global__ __launch_bounds__(1024) void k_scan3(int* __restrict__ rowptr,
                                                const int* __restrict__ boff) {
    int tid = threadIdx.x;
    int g = blockIdx.x * 1024 + tid;
    if (g == 0) rowptr[0] = 0;
    if (g < NN) rowptr[g + 1] += boff[blockIdx.x];
}

__global__ __launch_bounds__(256) void k_scatter(const int* __restrict__ ei,
                                                 const int* __restrict__ et,
                                                 const int* __restrict__ rowptr,
                                                 int* __restrict__ cursor,
                                                 unsigned* __restrict__ srow,
                                                 int* __restrict__ slot) {
    int e = blockIdx.x * 256 + threadIdx.x;
    if (e >= EE) return;
    int src = ei[e], dst = ei[EE + e], r = et[e];
    int pos = rowptr[dst] + atomicAdd(&cursor[dst], 1);
    srow[pos] = (unsigned)(src * RR + r);  // T row index
    slot[e] = pos;
}

// ---------- attention logits + segment max ----------
__global__ __launch_bounds__(256) void k_alpha(const int* __restrict__ ei,
                                               const int* __restrict__ et,
                                               const float* __restrict__ QT,
                                               const float* __restrict__ KT,
                                               float* __restrict__ alpha,
                                               unsigned* __restrict__ amaxU) {
    int e = blockIdx.x * 256 + threadIdx.x;
    if (e >= EE) return;
    int src = ei[e], dst = ei[EE + e], r = et[e];
    float4 qi = *(const float4*)(QT + (dst * RR + r) * 4);
    float4 kj = *(const float4*)(KT + (src * RR + r) * 4);
    float a0 = qi.x + kj.x, a1 = qi.y + kj.y, a2 = qi.z + kj.z, a3 = qi.w + kj.w;
    a0 = a0 > 0.f ? a0 : 0.2f * a0;
    a1 = a1 > 0.f ? a1 : 0.2f * a1;
    a2 = a2 > 0.f ? a2 : 0.2f * a2;
    a3 = a3 > 0.f ? a3 : 0.2f * a3;
    *(float4*)(alpha + e * 4) = make_float4(a0, a1, a2, a3);
    atomicMax(&amaxU[dst * 4 + 0], fmap(a0));
    atomicMax(&amaxU[dst * 4 + 1], fmap(a1));
    atomicMax(&amaxU[dst * 4 + 2], fmap(a2));
    atomicMax(&amaxU[dst * 4 + 3], fmap(a3));
}

// ---------- exp + segment sum; scatter ex to sorted slot ----------
__global__ __launch_bounds__(256) void k_exp(const int* __restrict__ ei,
                                             const float* __restrict__ alpha,
                                             const unsigned* __restrict__ amaxU,
                                             const int* __restrict__ slot,
                                             float* __restrict__ exs,
                                             float* __restrict__ denom) {
    int e = blockIdx.x * 256 + threadIdx.x;
    if (e >= EE) return;
    int dst = ei[EE + e];
    float4 a = *(const float4*)(alpha + e * 4);
    uint4 mu = *(const uint4*)(amaxU + dst * 4);
    float e0 = expf(a.x - funmap(mu.x));
    float e1 = expf(a.y - funmap(mu.y));
    float e2 = expf(a.z - funmap(mu.z));
    float e3 = expf(a.w - funmap(mu.w));
    int pos = slot[e];
    *(float4*)(exs + pos * 4) = make_float4(e0, e1, e2, e3);
    atomicAdd(&denom[dst * 4 + 0], e0);
    atomicAdd(&denom[dst * 4 + 1], e1);
    atomicAdd(&denom[dst * 4 + 2], e2);
    atomicAdd(&denom[dst * 4 + 3], e3);
}

// ---------- per-node gather-aggregate ----------
__global__ __launch_bounds__(128) void k_agg(const int* __restrict__ rowptr,
                                             const unsigned* __restrict__ srow,
                                             const float* __restrict__ exs,
                                             const float* __restrict__ denom,
                                             const unsigned short* __restrict__ T,
                                             const float* __restrict__ bias,
                                             float* __restrict__ out) {
    int n = blockIdx.x;
    int c = threadIdx.x;
    int h = c >> 5;
    int beg = rowptr[n], end = rowptr[n + 1];
    float acc = 0.f;
    int j = beg;
    for (; j + 4 <= end; j += 4) {
        unsigned r0 = srow[j], r1 = srow[j + 1], r2 = srow[j + 2], r3 = srow[j + 3];
        float w0 = exs[j * 4 + h], w1 = exs[(j + 1) * 4 + h];
        float w2 = exs[(j + 2) * 4 + h], w3 = exs[(j + 3) * 4 + h];
        float t0 = b2f(T[r0 * HCC + c]), t1 = b2f(T[r1 * HCC + c]);
        float t2 = b2f(T[r2 * HCC + c]), t3 = b2f(T[r3 * HCC + c]);
        acc += w0 * t0 + w1 * t1 + w2 * t2 + w3 * t3;
    }
    for (; j < end; ++j) acc += exs[j * 4 + h] * b2f(T[srow[j] * HCC + c]);
    float d = denom[n * 4 + h];
    out[n * HCC + c] = acc / (d + 1e-16f) + bias[c];
}

extern "C" void kernel_launch(void* const* d_in, const int* in_sizes, int n_in,
                              void* d_out, int out_size, void* d_ws, size_t ws_size,
                              hipStream_t stream) {
    const float* x    = (const float*)d_in[0];
    const int*   ei   = (const int*)d_in[1];
    const int*   et   = (const int*)d_in[2];
    const float* W    = (const float*)d_in[3];
    const float* qw   = (const float*)d_in[4];
    const float* kw   = (const float*)d_in[5];
    const float* bias = (const float*)d_in[6];
    float* out = (float*)d_out;
    char* ws = (char*)d_ws;

    // workspace layout (bytes) — total ~149.4 MB
    unsigned short* T  = (unsigned short*)(ws + 0);          // 102,400,000
    float* QT          = (float*)(ws + 102400000);           //   6,400,000
    float* KT          = (float*)(ws + 108800000);           //   6,400,000
    float* alpha       = (float*)(ws + 115200000);           //  12,800,000
    float* exs         = (float*)(ws + 128000000);           //  12,800,000
    float* Wq          = (float*)(ws + 140800000);           //      16,384
    float* Wk          = (float*)(ws + 140816384);           //      16,384
    unsigned* amaxU    = (unsigned*)(ws + 140832768);        //     800,000  (zeroed)
    float* denom       = (float*)(ws + 141632768);           //     800,000  (zeroed)
    int* deg           = (int*)(ws + 142432768);             //     200,000  (zeroed)
    int* cursor        = (int*)(ws + 142632768);             //     200,000  (zeroed)
    int* rowptr        = (int*)(ws + 142832768);             //     200,004
    int* bsum          = (int*)(ws + 143032960);             //         256
    int* boff          = (int*)(ws + 143033216);             //         256
    unsigned* srow     = (unsigned*)(ws + 143033472);        //   3,200,000
    int* slot          = (int*)(ws + 146233472);             //   3,200,000
    // transient (dead after k_T; stream-ordered reuse of alpha/exs regions):
    unsigned short* xb = (unsigned short*)(ws + 115200000);  //  12,800,000 (= alpha)
    unsigned short* Wt = (unsigned short*)(ws + 128000000);  //     262,144 (= exs)

    hipMemsetAsync(ws + 140832768, 0, 2000000, stream);  // amaxU|denom|deg|cursor

    k_cvt_x<<<3125, 256, 0, stream>>>(x, xb);
    k_cvt_wt<<<64, 256, 0, stream>>>(W, Wt);
    k_wqk<<<RR, 128, 0, stream>>>(W, qw, kw, Wq, Wk);
    k_qtkt<<<(NN * RR + 255) / 256, 256, 0, stream>>>(x, Wq, Wk, QT, KT);
    k_T<<<3126, 256, 0, stream>>>(xb, Wt, T);
    k_hist<<<(EE + 255) / 256, 256, 0, stream>>>(ei, deg);
    k_scan1<<<49, 1024, 0, stream>>>(deg, rowptr, bsum);
    k_scan2<<<1, 64, 0, stream>>>(bsum, boff);
    k_scan3<<<49, 1024, 0, stream>>>(rowptr, boff);
    k_scatter<<<(EE + 255) / 256, 256, 0, stream>>>(ei, et, rowptr, cursor, srow, slot);
    k_alpha<<<(EE + 255) / 256, 256, 0, stream>>>(ei, et, QT, KT, alpha, amaxU);
    k_exp<<<(EE + 255) / 256, 256, 0, stream>>>(ei, alpha, amaxU, slot, exs, denom);
    k_agg<<<NN, 128, 0, stream>>>(rowptr, srow, exs, denom, T, bias, out);
}

// Round 4
// 624.471 us; speedup vs baseline: 1.6074x; 1.2942x over previous
//
#include <hip/hip_runtime.h>

#define NN 50000
#define EE 800000
#define INC 128
#define HCC 128
#define RR 8
#define HH 4

typedef __attribute__((ext_vector_type(8))) short bf16x8;
typedef __attribute__((ext_vector_type(4))) float f32x4;

// ---------- helpers ----------
static __device__ __forceinline__ unsigned f2b_rne(float f) {
    unsigned u = __float_as_uint(f);
    return (u + 0x7FFFu + ((u >> 16) & 1u)) >> 16;
}
static __device__ __forceinline__ float b2f(unsigned short s) {
    return __uint_as_float(((unsigned)s) << 16);
}
// order-preserving float->uint map for atomicMax
static __device__ __forceinline__ unsigned fmap(float f) {
    unsigned u = __float_as_uint(f);
    return (u & 0x80000000u) ? ~u : (u | 0x80000000u);
}
static __device__ __forceinline__ float funmap(unsigned u) {
    unsigned b = (u & 0x80000000u) ? (u ^ 0x80000000u) : ~u;
    return __uint_as_float(b);
}

// ---------- prologue: x fp32 -> bf16 (row-major, feeds MFMA B-fragments) ----------
__global__ __launch_bounds__(256) void k_cvt_x(const float* __restrict__ x,
                                               unsigned short* __restrict__ xb) {
    int t = blockIdx.x * 256 + threadIdx.x;  // 800000 threads, 8 elems each
    const float4* p = (const float4*)x + t * 2;
    float4 v0 = p[0], v1 = p[1];
    uint4 pk;
    pk.x = f2b_rne(v0.x) | (f2b_rne(v0.y) << 16);
    pk.y = f2b_rne(v0.z) | (f2b_rne(v0.w) << 16);
    pk.z = f2b_rne(v1.x) | (f2b_rne(v1.y) << 16);
    pk.w = f2b_rne(v1.z) | (f2b_rne(v1.w) << 16);
    *((uint4*)xb + t) = pk;
}

// ---------- prologue: Wt[r][o][i] = bf16(W[r][i][o])  (A-fragment layout) ----------
__global__ __launch_bounds__(256) void k_cvt_wt(const float* __restrict__ W,
                                                unsigned short* __restrict__ Wt) {
    int t = blockIdx.x * 256 + threadIdx.x;  // 16384 threads
    int m = t & 127, kb = (t >> 7) & 15, r = t >> 11;
    unsigned short tmp[8];
#pragma unroll
    for (int j = 0; j < 8; ++j)
        tmp[j] = (unsigned short)f2b_rne(W[((r << 7) + (kb << 3) + j) * 128 + m]);
    uint4 pk;
    pk.x = tmp[0] | ((unsigned)tmp[1] << 16);
    pk.y = tmp[2] | ((unsigned)tmp[3] << 16);
    pk.z = tmp[4] | ((unsigned)tmp[5] << 16);
    pk.w = tmp[6] | ((unsigned)tmp[7] << 16);
    *(uint4*)(Wt + ((r << 7) + m) * 128 + (kb << 3)) = pk;
}

// ---------- K0: combined QK projection matrix, transposed bf16 ----------
// Wqkt[c][i], c=0..31: r=c>>2,h=c&3 -> sum_o W[r,i,o]*q[o,h]
//            c=32..63: same with k.  [64][128] bf16, K-contiguous (A-frag layout).
__global__ __launch_bounds__(128) void k_wqk(const float* __restrict__ W,
                                             const float* __restrict__ qw,
                                             const float* __restrict__ kw,
                                             unsigned short* __restrict__ Wqkt) {
    int r = blockIdx.x, i = threadIdx.x;
    const float* wrow = W + (r * INC + i) * HCC;
    float aq0 = 0, aq1 = 0, aq2 = 0, aq3 = 0;
    float ak0 = 0, ak1 = 0, ak2 = 0, ak3 = 0;
    for (int o = 0; o < HCC; ++o) {
        float w = wrow[o];
        float4 qv = *(const float4*)(qw + o * 4);
        float4 kv = *(const float4*)(kw + o * 4);
        aq0 = fmaf(w, qv.x, aq0); aq1 = fmaf(w, qv.y, aq1);
        aq2 = fmaf(w, qv.z, aq2); aq3 = fmaf(w, qv.w, aq3);
        ak0 = fmaf(w, kv.x, ak0); ak1 = fmaf(w, kv.y, ak1);
        ak2 = fmaf(w, kv.z, ak2); ak3 = fmaf(w, kv.w, ak3);
    }
    int cq = r * 4, ck = 32 + r * 4;
    Wqkt[(cq + 0) * 128 + i] = (unsigned short)f2b_rne(aq0);
    Wqkt[(cq + 1) * 128 + i] = (unsigned short)f2b_rne(aq1);
    Wqkt[(cq + 2) * 128 + i] = (unsigned short)f2b_rne(aq2);
    Wqkt[(cq + 3) * 128 + i] = (unsigned short)f2b_rne(aq3);
    Wqkt[(ck + 0) * 128 + i] = (unsigned short)f2b_rne(ak0);
    Wqkt[(ck + 1) * 128 + i] = (unsigned short)f2b_rne(ak1);
    Wqkt[(ck + 2) * 128 + i] = (unsigned short)f2b_rne(ak2);
    Wqkt[(ck + 3) * 128 + i] = (unsigned short)f2b_rne(ak3);
}

// ---------- K1 (MFMA): [QT|KT] = x @ Wqk  (skinny GEMM, M=64 cols) ----------
// A = Wqkt (M=64, K=128), B = x node-tile (N=16). D: col(lane&15)=node,
// row=(lane>>4)*4+reg -> lane holds 4 consecutive cols = one (r,h0..3) float4.
__global__ __launch_bounds__(256) void k_qk(const unsigned short* __restrict__ xb,
                                            const unsigned short* __restrict__ Wqkt,
                                            float* __restrict__ QT,
                                            float* __restrict__ KT) {
    int wave = (blockIdx.x * 256 + threadIdx.x) >> 6;  // 2 node-tiles per wave
    int lane = threadIdx.x & 63;
    int nt0 = wave * 2, nt1 = nt0 + 1;
    if (nt0 >= 3125) return;
    bool has1 = nt1 < 3125;
    int ln = lane & 15, kq = lane >> 4;

    const unsigned short* x0 = xb + (nt0 * 16 + ln) * 128 + kq * 8;
    const unsigned short* x1 = xb + ((has1 ? nt1 : nt0) * 16 + ln) * 128 + kq * 8;
    bf16x8 b0[4], b1[4];
#pragma unroll
    for (int ks = 0; ks < 4; ++ks) {
        b0[ks] = *(const bf16x8*)(x0 + ks * 32);
        b1[ks] = *(const bf16x8*)(x1 + ks * 32);
    }
    const unsigned short* ab = Wqkt + ln * 128 + kq * 8;
#pragma unroll
    for (int mg = 0; mg < 4; ++mg) {
        f32x4 acc0 = {0.f, 0.f, 0.f, 0.f};
        f32x4 acc1 = {0.f, 0.f, 0.f, 0.f};
#pragma unroll
        for (int ks = 0; ks < 4; ++ks) {
            bf16x8 a = *(const bf16x8*)(ab + mg * 2048 + ks * 32);
            acc0 = __builtin_amdgcn_mfma_f32_16x16x32_bf16(a, b0[ks], acc0, 0, 0, 0);
            acc1 = __builtin_amdgcn_mfma_f32_16x16x32_bf16(a, b1[ks], acc1, 0, 0, 0);
        }
        float* base = (mg < 2) ? QT : KT;
        int rr = (mg & 1) * 4 + kq;  // relation index
        *(f32x4*)(base + ((nt0 * 16 + ln) * 8 + rr) * 4) = acc0;
        if (has1) *(f32x4*)(base + ((nt1 * 16 + ln) * 8 + rr) * 4) = acc1;
    }
}

// ---------- K2 (MFMA): T[n,r,:] = x[n,:] @ W_r, computed transposed ----------
__global__ __launch_bounds__(256) void k_T(const unsigned short* __restrict__ xb,
                                           const unsigned short* __restrict__ Wt,
                                           unsigned short* __restrict__ T) {
    int wave = (blockIdx.x * 256 + threadIdx.x) >> 6;  // 0..12503
    int lane = threadIdx.x & 63;
    int r = wave & 7;
    int p = wave >> 3;          // 0..1562
    int nt0 = p * 2, nt1 = nt0 + 1;
    bool has1 = nt1 < 3125;
    int ln = lane & 15, kq = lane >> 4;

    const unsigned short* x0 = xb + (nt0 * 16 + ln) * 128 + kq * 8;
    const unsigned short* x1 = xb + ((has1 ? nt1 : nt0) * 16 + ln) * 128 + kq * 8;
    bf16x8 b0[4], b1[4];
#pragma unroll
    for (int ks = 0; ks < 4; ++ks) {
        b0[ks] = *(const bf16x8*)(x0 + ks * 32);
        b1[ks] = *(const bf16x8*)(x1 + ks * 32);
    }
    const unsigned short* wb = Wt + (r * 128 + ln) * 128 + kq * 8;
#pragma unroll
    for (int mg = 0; mg < 8; ++mg) {
        f32x4 acc0 = {0.f, 0.f, 0.f, 0.f};
        f32x4 acc1 = {0.f, 0.f, 0.f, 0.f};
#pragma unroll
        for (int ks = 0; ks < 4; ++ks) {
            bf16x8 a = *(const bf16x8*)(wb + mg * 2048 + ks * 32);
            acc0 = __builtin_amdgcn_mfma_f32_16x16x32_bf16(a, b0[ks], acc0, 0, 0, 0);
            acc1 = __builtin_amdgcn_mfma_f32_16x16x32_bf16(a, b1[ks], acc1, 0, 0, 0);
        }
        uint2 pk0, pk1;
        pk0.x = f2b_rne(acc0[0]) | (f2b_rne(acc0[1]) << 16);
        pk0.y = f2b_rne(acc0[2]) | (f2b_rne(acc0[3]) << 16);
        pk1.x = f2b_rne(acc1[0]) | (f2b_rne(acc1[1]) << 16);
        pk1.y = f2b_rne(acc1[2]) | (f2b_rne(acc1[3]) << 16);
        int c = mg * 16 + kq * 4;
        *(uint2*)(T + ((nt0 * 16 + ln) * 8 + r) * 128 + c) = pk0;
        if (has1) *(uint2*)(T + ((nt1 * 16 + ln) * 8 + r) * 128 + c) = pk1;
    }
}

// ---------- CSR build ----------
__global__ __launch_bounds__(256) void k_hist(const int* __restrict__ ei,
                                              int* __restrict__ deg) {
    int e = blockIdx.x * 256 + threadIdx.x;
    if (e >= EE) return;
    atomicAdd(&deg[ei[EE + e]], 1);
}

__global__ __launch_bounds__(1024) void k_scan1(const int* __restrict__ deg,
                                                int* __restrict__ rowptr,
                                                int* __restrict__ bsum) {
    __shared__ int s[1024];
    int tid = threadIdx.x;
    int g = blockIdx.x * 1024 + tid;
    int v = (g < NN) ? deg[g] : 0;
    s[tid] = v;
    __syncthreads();
    for (int off = 1; off < 1024; off <<= 1) {
        int t = (tid >= off) ? s[tid - off] : 0;
        __syncthreads();
        s[tid] += t;
        __syncthreads();
    }
    if (g < NN) rowptr[g + 1] = s[tid];  // chunk-local inclusive
    if (tid == 1023) bsum[blockIdx.x] = s[1023];
}

__global__ void k_scan2(const int* __restrict__ bsum, int* __restrict__ boff) {
    int tid = threadIdx.x;  // 64 = 1 wave
    const int NB = (NN + 1023) / 1024;  // 49
    int v = (tid < NB) ? bsum[tid] : 0;
    int orig = v;
    for (int off = 1; off < 64; off <<= 1) {
        int t = __shfl_up(v, off);
        if (tid >= off) v += t;
    }
    if (tid < NB) boff[tid] = v - orig;  // exclusive
}

__global__ __launch_bounds__(1024) void k_scan3(int* __restrict__ rowptr,
                                                const int* __restrict__ boff) {
    int tid = threadIdx.x;
    int g = blockIdx.x * 1024 + tid;
    if (g == 0) rowptr[0] = 0;
    if (g < NN) rowptr[g + 1] += boff[blockIdx.x];
}

__global__ __launch_bounds__(256) void k_scatter(const int* __restrict__ ei,
                                                 const int* __restrict__ et,
                                                 const int* __restrict__ rowptr,
                                                 int* __restrict__ cursor,
                                                 unsigned* __restrict__ srow,
                                                 int* __restrict__ slot) {
    int e = blockIdx.x * 256 + threadIdx.x;
    if (e >= EE) return;
    int src = ei[e], dst = ei[EE + e], r = et[e];
    int pos = rowptr[dst] + atomicAdd(&cursor[dst], 1);
    srow[pos] = (unsigned)(src * RR + r);  // T row index
    slot[e] = pos;
}

// ---------- attention logits + segment max ----------
__global__ __launch_bounds__(256) void k_alpha(const int* __restrict__ ei,
                                               const int* __restrict__ et,
                                               const float* __restrict__ QT,
                                               const float* __restrict__ KT,
                                               float* __restrict__ alpha,
                                               unsigned* __restrict__ amaxU) {
    int e = blockIdx.x * 256 + threadIdx.x;
    if (e >= EE) return;
    int src = ei[e], dst = ei[EE + e], r = et[e];
    float4 qi = *(const float4*)(QT + (dst * RR + r) * 4);
    float4 kj = *(const float4*)(KT + (src * RR + r) * 4);
    float a0 = qi.x + kj.x, a1 = qi.y + kj.y, a2 = qi.z + kj.z, a3 = qi.w + kj.w;
    a0 = a0 > 0.f ? a0 : 0.2f * a0;
    a1 = a1 > 0.f ? a1 : 0.2f * a1;
    a2 = a2 > 0.f ? a2 : 0.2f * a2;
    a3 = a3 > 0.f ? a3 : 0.2f * a3;
    *(float4*)(alpha + e * 4) = make_float4(a0, a1, a2, a3);
    atomicMax(&amaxU[dst * 4 + 0], fmap(a0));
    atomicMax(&amaxU[dst * 4 + 1], fmap(a1));
    atomicMax(&amaxU[dst * 4 + 2], fmap(a2));
    atomicMax(&amaxU[dst * 4 + 3], fmap(a3));
}

// ---------- exp + segment sum; scatter ex to sorted slot ----------
__global__ __launch_bounds__(256) void k_exp(const int* __restrict__ ei,
                                             const float* __restrict__ alpha,
                                             const unsigned* __restrict__ amaxU,
                                             const int* __restrict__ slot,
                                             float* __restrict__ exs,
                                             float* __restrict__ denom) {
    int e = blockIdx.x * 256 + threadIdx.x;
    if (e >= EE) return;
    int dst = ei[EE + e];
    float4 a = *(const float4*)(alpha + e * 4);
    uint4 mu = *(const uint4*)(amaxU + dst * 4);
    float e0 = expf(a.x - funmap(mu.x));
    float e1 = expf(a.y - funmap(mu.y));
    float e2 = expf(a.z - funmap(mu.z));
    float e3 = expf(a.w - funmap(mu.w));
    int pos = slot[e];
    *(float4*)(exs + pos * 4) = make_float4(e0, e1, e2, e3);
    atomicAdd(&denom[dst * 4 + 0], e0);
    atomicAdd(&denom[dst * 4 + 1], e1);
    atomicAdd(&denom[dst * 4 + 2], e2);
    atomicAdd(&denom[dst * 4 + 3], e3);
}

// ---------- per-node gather-aggregate ----------
__global__ __launch_bounds__(128) void k_agg(const int* __restrict__ rowptr,
                                             const unsigned* __restrict__ srow,
                                             const float* __restrict__ exs,
                                             const float* __restrict__ denom,
                                             const unsigned short* __restrict__ T,
                                             const float* __restrict__ bias,
                                             float* __restrict__ out) {
    int n = blockIdx.x;
    int c = threadIdx.x;
    int h = c >> 5;
    int beg = rowptr[n], end = rowptr[n + 1];
    float acc = 0.f;
    int j = beg;
    for (; j + 4 <= end; j += 4) {
        unsigned r0 = srow[j], r1 = srow[j + 1], r2 = srow[j + 2], r3 = srow[j + 3];
        float w0 = exs[j * 4 + h], w1 = exs[(j + 1) * 4 + h];
        float w2 = exs[(j + 2) * 4 + h], w3 = exs[(j + 3) * 4 + h];
        float t0 = b2f(T[r0 * HCC + c]), t1 = b2f(T[r1 * HCC + c]);
        float t2 = b2f(T[r2 * HCC + c]), t3 = b2f(T[r3 * HCC + c]);
        acc += w0 * t0 + w1 * t1 + w2 * t2 + w3 * t3;
    }
    for (; j < end; ++j) acc += exs[j * 4 + h] * b2f(T[srow[j] * HCC + c]);
    float d = denom[n * 4 + h];
    out[n * HCC + c] = acc / (d + 1e-16f) + bias[c];
}

extern "C" void kernel_launch(void* const* d_in, const int* in_sizes, int n_in,
                              void* d_out, int out_size, void* d_ws, size_t ws_size,
                              hipStream_t stream) {
    const float* x    = (const float*)d_in[0];
    const int*   ei   = (const int*)d_in[1];
    const int*   et   = (const int*)d_in[2];
    const float* W    = (const float*)d_in[3];
    const float* qw   = (const float*)d_in[4];
    const float* kw   = (const float*)d_in[5];
    const float* bias = (const float*)d_in[6];
    float* out = (float*)d_out;
    char* ws = (char*)d_ws;

    // workspace layout (bytes) — total ~149.4 MB
    unsigned short* T  = (unsigned short*)(ws + 0);          // 102,400,000
    float* QT          = (float*)(ws + 102400000);           //   6,400,000
    float* KT          = (float*)(ws + 108800000);           //   6,400,000
    float* alpha       = (float*)(ws + 115200000);           //  12,800,000
    float* exs         = (float*)(ws + 128000000);           //  12,800,000
    unsigned short* Wqkt = (unsigned short*)(ws + 140800000);//      16,384
    unsigned* amaxU    = (unsigned*)(ws + 140832768);        //     800,000  (zeroed)
    float* denom       = (float*)(ws + 141632768);           //     800,000  (zeroed)
    int* deg           = (int*)(ws + 142432768);             //     200,000  (zeroed)
    int* cursor        = (int*)(ws + 142632768);             //     200,000  (zeroed)
    int* rowptr        = (int*)(ws + 142832768);             //     200,004
    int* bsum          = (int*)(ws + 143032960);             //         256
    int* boff          = (int*)(ws + 143033216);             //         256
    unsigned* srow     = (unsigned*)(ws + 143033472);        //   3,200,000
    int* slot          = (int*)(ws + 146233472);             //   3,200,000
    // transient (dead after k_T/k_qk; stream-ordered reuse of alpha/exs regions):
    unsigned short* xb = (unsigned short*)(ws + 115200000);  //  12,800,000 (= alpha)
    unsigned short* Wt = (unsigned short*)(ws + 128000000);  //     262,144 (= exs)

    hipMemsetAsync(ws + 140832768, 0, 2000000, stream);  // amaxU|denom|deg|cursor

    k_cvt_x<<<3125, 256, 0, stream>>>(x, xb);
    k_cvt_wt<<<64, 256, 0, stream>>>(W, Wt);
    k_wqk<<<RR, 128, 0, stream>>>(W, qw, kw, Wqkt);
    k_qk<<<391, 256, 0, stream>>>(xb, Wqkt, QT, KT);
    k_T<<<3126, 256, 0, stream>>>(xb, Wt, T);
    k_hist<<<(EE + 255) / 256, 256, 0, stream>>>(ei, deg);
    k_scan1<<<49, 1024, 0, stream>>>(deg, rowptr, bsum);
    k_scan2<<<1, 64, 0, stream>>>(bsum, boff);
    k_scan3<<<49, 1024, 0, stream>>>(rowptr, boff);
    k_scatter<<<(EE + 255) / 256, 256, 0, stream>>>(ei, et, rowptr, cursor, srow, slot);
    k_alpha<<<(EE + 255) / 256, 256, 0, stream>>>(ei, et, QT, KT, alpha, amaxU);
    k_exp<<<(EE + 255) / 256, 256, 0, stream>>>(ei, alpha, amaxU, slot, exs, denom);
    k_agg<<<NN, 128, 0, stream>>>(rowptr, srow, exs, denom, T, bias, out);
}

// Round 7
// 316.310 us; speedup vs baseline: 3.1733x; 1.9742x over previous
//
#include <hip/hip_runtime.h>

#define NN 50000
#define EE 800000
#define INC 128
#define HCC 128
#define RR 8
#define HH 4
#define CHUNK 256

typedef __attribute__((ext_vector_type(8))) short bf16x8;
typedef __attribute__((ext_vector_type(4))) float f32x4;

// ---------- helpers ----------
static __device__ __forceinline__ unsigned f2b_rne(float f) {
    unsigned u = __float_as_uint(f);
    return (u + 0x7FFFu + ((u >> 16) & 1u)) >> 16;
}
static __device__ __forceinline__ float b2f(unsigned short s) {
    return __uint_as_float(((unsigned)s) << 16);
}

// ---------- prologue: x fp32 -> bf16 (row-major, feeds MFMA B-fragments) ----------
__global__ __launch_bounds__(256) void k_cvt_x(const float* __restrict__ x,
                                               unsigned short* __restrict__ xb) {
    int t = blockIdx.x * 256 + threadIdx.x;  // 800000 threads, 8 elems each
    const float4* p = (const float4*)x + t * 2;
    float4 v0 = p[0], v1 = p[1];
    uint4 pk;
    pk.x = f2b_rne(v0.x) | (f2b_rne(v0.y) << 16);
    pk.y = f2b_rne(v0.z) | (f2b_rne(v0.w) << 16);
    pk.z = f2b_rne(v1.x) | (f2b_rne(v1.y) << 16);
    pk.w = f2b_rne(v1.z) | (f2b_rne(v1.w) << 16);
    *((uint4*)xb + t) = pk;
}

// ---------- prologue: Wt[r][o][i] = bf16(W[r][i][o])  (A-fragment layout) ----------
__global__ __launch_bounds__(256) void k_cvt_wt(const float* __restrict__ W,
                                                unsigned short* __restrict__ Wt) {
    int t = blockIdx.x * 256 + threadIdx.x;  // 16384 threads
    int m = t & 127, kb = (t >> 7) & 15, r = t >> 11;
    unsigned short tmp[8];
#pragma unroll
    for (int j = 0; j < 8; ++j)
        tmp[j] = (unsigned short)f2b_rne(W[((r << 7) + (kb << 3) + j) * 128 + m]);
    uint4 pk;
    pk.x = tmp[0] | ((unsigned)tmp[1] << 16);
    pk.y = tmp[2] | ((unsigned)tmp[3] << 16);
    pk.z = tmp[4] | ((unsigned)tmp[5] << 16);
    pk.w = tmp[6] | ((unsigned)tmp[7] << 16);
    *(uint4*)(Wt + ((r << 7) + m) * 128 + (kb << 3)) = pk;
}

// ---------- K0: combined QK projection matrix, transposed bf16 ----------
__global__ __launch_bounds__(128) void k_wqk(const float* __restrict__ W,
                                             const float* __restrict__ qw,
                                             const float* __restrict__ kw,
                                             unsigned short* __restrict__ Wqkt) {
    int r = blockIdx.x, i = threadIdx.x;
    const float* wrow = W + (r * INC + i) * HCC;
    float aq0 = 0, aq1 = 0, aq2 = 0, aq3 = 0;
    float ak0 = 0, ak1 = 0, ak2 = 0, ak3 = 0;
    for (int o = 0; o < HCC; ++o) {
        float w = wrow[o];
        float4 qv = *(const float4*)(qw + o * 4);
        float4 kv = *(const float4*)(kw + o * 4);
        aq0 = fmaf(w, qv.x, aq0); aq1 = fmaf(w, qv.y, aq1);
        aq2 = fmaf(w, qv.z, aq2); aq3 = fmaf(w, qv.w, aq3);
        ak0 = fmaf(w, kv.x, ak0); ak1 = fmaf(w, kv.y, ak1);
        ak2 = fmaf(w, kv.z, ak2); ak3 = fmaf(w, kv.w, ak3);
    }
    int cq = r * 4, ck = 32 + r * 4;
    Wqkt[(cq + 0) * 128 + i] = (unsigned short)f2b_rne(aq0);
    Wqkt[(cq + 1) * 128 + i] = (unsigned short)f2b_rne(aq1);
    Wqkt[(cq + 2) * 128 + i] = (unsigned short)f2b_rne(aq2);
    Wqkt[(cq + 3) * 128 + i] = (unsigned short)f2b_rne(aq3);
    Wqkt[(ck + 0) * 128 + i] = (unsigned short)f2b_rne(ak0);
    Wqkt[(ck + 1) * 128 + i] = (unsigned short)f2b_rne(ak1);
    Wqkt[(ck + 2) * 128 + i] = (unsigned short)f2b_rne(ak2);
    Wqkt[(ck + 3) * 128 + i] = (unsigned short)f2b_rne(ak3);
}

// ---------- K1 (MFMA): [QT|KT] = x @ Wqk  (skinny GEMM, M=64 cols) ----------
__global__ __launch_bounds__(256) void k_qk(const unsigned short* __restrict__ xb,
                                            const unsigned short* __restrict__ Wqkt,
                                            float* __restrict__ QT,
                                            float* __restrict__ KT) {
    int wave = (blockIdx.x * 256 + threadIdx.x) >> 6;  // 2 node-tiles per wave
    int lane = threadIdx.x & 63;
    int nt0 = wave * 2, nt1 = nt0 + 1;
    if (nt0 >= 3125) return;
    bool has1 = nt1 < 3125;
    int ln = lane & 15, kq = lane >> 4;

    const unsigned short* x0 = xb + (nt0 * 16 + ln) * 128 + kq * 8;
    const unsigned short* x1 = xb + ((has1 ? nt1 : nt0) * 16 + ln) * 128 + kq * 8;
    bf16x8 b0[4], b1[4];
#pragma unroll
    for (int ks = 0; ks < 4; ++ks) {
        b0[ks] = *(const bf16x8*)(x0 + ks * 32);
        b1[ks] = *(const bf16x8*)(x1 + ks * 32);
    }
    const unsigned short* ab = Wqkt + ln * 128 + kq * 8;
#pragma unroll
    for (int mg = 0; mg < 4; ++mg) {
        f32x4 acc0 = {0.f, 0.f, 0.f, 0.f};
        f32x4 acc1 = {0.f, 0.f, 0.f, 0.f};
#pragma unroll
        for (int ks = 0; ks < 4; ++ks) {
            bf16x8 a = *(const bf16x8*)(ab + mg * 2048 + ks * 32);
            acc0 = __builtin_amdgcn_mfma_f32_16x16x32_bf16(a, b0[ks], acc0, 0, 0, 0);
            acc1 = __builtin_amdgcn_mfma_f32_16x16x32_bf16(a, b1[ks], acc1, 0, 0, 0);
        }
        float* base = (mg < 2) ? QT : KT;
        int rr = (mg & 1) * 4 + kq;  // relation index
        *(f32x4*)(base + ((nt0 * 16 + ln) * 8 + rr) * 4) = acc0;
        if (has1) *(f32x4*)(base + ((nt1 * 16 + ln) * 8 + rr) * 4) = acc1;
    }
}

// ---------- K2 (MFMA): T[n,r,:] = x[n,:] @ W_r, computed transposed ----------
__global__ __launch_bounds__(256) void k_T(const unsigned short* __restrict__ xb,
                                           const unsigned short* __restrict__ Wt,
                                           unsigned short* __restrict__ T) {
    int wave = (blockIdx.x * 256 + threadIdx.x) >> 6;  // 0..12503
    int lane = threadIdx.x & 63;
    int r = wave & 7;
    int p = wave >> 3;          // 0..1562
    int nt0 = p * 2, nt1 = nt0 + 1;
    bool has1 = nt1 < 3125;
    int ln = lane & 15, kq = lane >> 4;

    const unsigned short* x0 = xb + (nt0 * 16 + ln) * 128 + kq * 8;
    const unsigned short* x1 = xb + ((has1 ? nt1 : nt0) * 16 + ln) * 128 + kq * 8;
    bf16x8 b0[4], b1[4];
#pragma unroll
    for (int ks = 0; ks < 4; ++ks) {
        b0[ks] = *(const bf16x8*)(x0 + ks * 32);
        b1[ks] = *(const bf16x8*)(x1 + ks * 32);
    }
    const unsigned short* wb = Wt + (r * 128 + ln) * 128 + kq * 8;
#pragma unroll
    for (int mg = 0; mg < 8; ++mg) {
        f32x4 acc0 = {0.f, 0.f, 0.f, 0.f};
        f32x4 acc1 = {0.f, 0.f, 0.f, 0.f};
#pragma unroll
        for (int ks = 0; ks < 4; ++ks) {
            bf16x8 a = *(const bf16x8*)(wb + mg * 2048 + ks * 32);
            acc0 = __builtin_amdgcn_mfma_f32_16x16x32_bf16(a, b0[ks], acc0, 0, 0, 0);
            acc1 = __builtin_amdgcn_mfma_f32_16x16x32_bf16(a, b1[ks], acc1, 0, 0, 0);
        }
        uint2 pk0, pk1;
        pk0.x = f2b_rne(acc0[0]) | (f2b_rne(acc0[1]) << 16);
        pk0.y = f2b_rne(acc0[2]) | (f2b_rne(acc0[3]) << 16);
        pk1.x = f2b_rne(acc1[0]) | (f2b_rne(acc1[1]) << 16);
        pk1.y = f2b_rne(acc1[2]) | (f2b_rne(acc1[3]) << 16);
        int c = mg * 16 + kq * 4;
        *(uint2*)(T + ((nt0 * 16 + ln) * 8 + r) * 128 + c) = pk0;
        if (has1) *(uint2*)(T + ((nt1 * 16 + ln) * 8 + r) * 128 + c) = pk1;
    }
}

// ---------- CSR build ----------
__global__ __launch_bounds__(256) void k_hist(const int* __restrict__ ei,
                                              int* __restrict__ deg) {
    int e = blockIdx.x * 256 + threadIdx.x;
    if (e >= EE) return;
    atomicAdd(&deg[ei[EE + e]], 1);
}

__global__ __launch_bounds__(1024) void k_scan1(const int* __restrict__ deg,
                                                int* __restrict__ rowptr,
                                                int* __restrict__ bsum) {
    __shared__ int s[1024];
    int tid = threadIdx.x;
    int g = blockIdx.x * 1024 + tid;
    int v = (g < NN) ? deg[g] : 0;
    s[tid] = v;
    __syncthreads();
    for (int off = 1; off < 1024; off <<= 1) {
        int t = (tid >= off) ? s[tid - off] : 0;
        __syncthreads();
        s[tid] += t;
        __syncthreads();
    }
    if (g < NN) rowptr[g + 1] = s[tid];  // chunk-local inclusive
    if (tid == 1023) bsum[blockIdx.x] = s[1023];
}

__global__ void k_scan2(const int* __restrict__ bsum, int* __restrict__ boff) {
    int tid = threadIdx.x;  // 64 = 1 wave
    const int NB = (NN + 1023) / 1024;  // 49
    int v = (tid < NB) ? bsum[tid] : 0;
    int orig = v;
    for (int off = 1; off < 64; off <<= 1) {
        int t = __shfl_up(v, off);
        if (tid >= off) v += t;
    }
    if (tid < NB) boff[tid] = v - orig;  // exclusive
}

__global__ __launch_bounds__(1024) void k_scan3(int* __restrict__ rowptr,
                                                const int* __restrict__ boff) {
    int tid = threadIdx.x;
    int g = blockIdx.x * 1024 + tid;
    if (g == 0) rowptr[0] = 0;
    if (g < NN) rowptr[g + 1] += boff[blockIdx.x];
}

__global__ __launch_bounds__(256) void k_scatter(const int* __restrict__ ei,
                                                 const int* __restrict__ et,
                                                 const int* __restrict__ rowptr,
                                                 int* __restrict__ cursor,
                                                 unsigned* __restrict__ srow) {
    int e = blockIdx.x * 256 + threadIdx.x;
    if (e >= EE) return;
    int src = ei[e], dst = ei[EE + e], r = et[e];
    int pos = rowptr[dst] + atomicAdd(&cursor[dst], 1);
    srow[pos] = (unsigned)(src * RR + r);  // T row index (src*8+r)
}

// ---------- fused attention + aggregate: one wave per node, flash-style ----------
// Per chunk of <=256 edges: edge-parallel logits (KT gather) -> wave max ->
// online rescale -> exp+denom -> channel-parallel sum of ex * T[src,r].
__global__ __launch_bounds__(64) void k_attagg(const int* __restrict__ rowptr,
                                               const unsigned* __restrict__ srow,
                                               const float* __restrict__ QT,
                                               const float* __restrict__ KT,
                                               const unsigned short* __restrict__ T,
                                               const float* __restrict__ bias,
                                               float* __restrict__ out) {
    __shared__ float als[CHUNK * 4];
    __shared__ unsigned srw[CHUNK];
    __shared__ float qs[32];
    const int n = blockIdx.x;
    const int lane = threadIdx.x;
    const int h = lane >> 4;       // head for channels 2*lane, 2*lane+1
    const int c = lane * 2;
    const int beg = rowptr[n], end = rowptr[n + 1];

    if (lane < 32) qs[lane] = QT[n * 32 + lane];
    __syncthreads();

    float m0 = -3.0e38f, m1 = -3.0e38f, m2 = -3.0e38f, m3 = -3.0e38f;
    float d0 = 0.f, d1 = 0.f, d2 = 0.f, d3 = 0.f;
    float accx = 0.f, accy = 0.f;

    for (int j0 = beg; j0 < end; j0 += CHUNK) {
        const int cnt = min(CHUNK, end - j0);
        // --- phase A: edge-parallel logits + local max ---
        float lm0 = -3.0e38f, lm1 = -3.0e38f, lm2 = -3.0e38f, lm3 = -3.0e38f;
        for (int jj = lane; jj < cnt; jj += 64) {
            unsigned sr = srow[j0 + jj];
            srw[jj] = sr;
            int r = sr & 7;
            float4 kj = *(const float4*)(KT + sr * 4);
            float a0 = qs[r * 4 + 0] + kj.x;
            float a1 = qs[r * 4 + 1] + kj.y;
            float a2 = qs[r * 4 + 2] + kj.z;
            float a3 = qs[r * 4 + 3] + kj.w;
            a0 = a0 > 0.f ? a0 : 0.2f * a0;
            a1 = a1 > 0.f ? a1 : 0.2f * a1;
            a2 = a2 > 0.f ? a2 : 0.2f * a2;
            a3 = a3 > 0.f ? a3 : 0.2f * a3;
            als[jj * 4 + 0] = a0; als[jj * 4 + 1] = a1;
            als[jj * 4 + 2] = a2; als[jj * 4 + 3] = a3;
            lm0 = fmaxf(lm0, a0); lm1 = fmaxf(lm1, a1);
            lm2 = fmaxf(lm2, a2); lm3 = fmaxf(lm3, a3);
        }
        __syncthreads();
        // --- wave max reduce ---
#pragma unroll
        for (int off = 1; off < 64; off <<= 1) {
            lm0 = fmaxf(lm0, __shfl_xor(lm0, off));
            lm1 = fmaxf(lm1, __shfl_xor(lm1, off));
            lm2 = fmaxf(lm2, __shfl_xor(lm2, off));
            lm3 = fmaxf(lm3, __shfl_xor(lm3, off));
        }
        // --- online rescale ---
        float nm0 = fmaxf(m0, lm0), nm1 = fmaxf(m1, lm1);
        float nm2 = fmaxf(m2, lm2), nm3 = fmaxf(m3, lm3);
        float s0 = expf(m0 - nm0), s1 = expf(m1 - nm1);
        float s2 = expf(m2 - nm2), s3 = expf(m3 - nm3);
        d0 *= s0; d1 *= s1; d2 *= s2; d3 *= s3;
        float sh = h == 0 ? s0 : h == 1 ? s1 : h == 2 ? s2 : s3;
        accx *= sh; accy *= sh;
        m0 = nm0; m1 = nm1; m2 = nm2; m3 = nm3;
        // --- phase D: exp + denom partial (same lane->jj map as phase A) ---
        float p0 = 0.f, p1 = 0.f, p2 = 0.f, p3 = 0.f;
        for (int jj = lane; jj < cnt; jj += 64) {
            float e0 = expf(als[jj * 4 + 0] - m0);
            float e1 = expf(als[jj * 4 + 1] - m1);
            float e2 = expf(als[jj * 4 + 2] - m2);
            float e3 = expf(als[jj * 4 + 3] - m3);
            als[jj * 4 + 0] = e0; als[jj * 4 + 1] = e1;
            als[jj * 4 + 2] = e2; als[jj * 4 + 3] = e3;
            p0 += e0; p1 += e1; p2 += e2; p3 += e3;
        }
#pragma unroll
        for (int off = 1; off < 64; off <<= 1) {
            p0 += __shfl_xor(p0, off);
            p1 += __shfl_xor(p1, off);
            p2 += __shfl_xor(p2, off);
            p3 += __shfl_xor(p3, off);
        }
        d0 += p0; d1 += p1; d2 += p2; d3 += p3;
        __syncthreads();
        // --- phase E: channel-parallel weighted T accumulate ---
        for (int jj = 0; jj < cnt; ++jj) {
            float w = als[jj * 4 + h];
            unsigned pk = *(const unsigned*)(T + srw[jj] * 128 + c);
            accx = fmaf(w, b2f((unsigned short)(pk & 0xFFFF)), accx);
            accy = fmaf(w, b2f((unsigned short)(pk >> 16)), accy);
        }
        __syncthreads();
    }
    float dh = h == 0 ? d0 : h == 1 ? d1 : h == 2 ? d2 : d3;
    float inv = 1.f / (dh + 1e-16f);
    out[n * 128 + c] = accx * inv + bias[c];
    out[n * 128 + c + 1] = accy * inv + bias[c + 1];
}

extern "C" void kernel_launch(void* const* d_in, const int* in_sizes, int n_in,
                              void* d_out, int out_size, void* d_ws, size_t ws_size,
                              hipStream_t stream) {
    const float* x    = (const float*)d_in[0];
    const int*   ei   = (const int*)d_in[1];
    const int*   et   = (const int*)d_in[2];
    const float* W    = (const float*)d_in[3];
    const float* qw   = (const float*)d_in[4];
    const float* kw   = (const float*)d_in[5];
    const float* bias = (const float*)d_in[6];
    float* out = (float*)d_out;
    char* ws = (char*)d_ws;

    // workspace layout (bytes) — total ~132 MB
    unsigned short* T    = (unsigned short*)(ws + 0);          // 102,400,000
    float* QT            = (float*)(ws + 102400000);           //   6,400,000
    float* KT            = (float*)(ws + 108800000);           //   6,400,000
    unsigned short* Wqkt = (unsigned short*)(ws + 115200000);  //      16,384
    int* deg             = (int*)(ws + 115220480);             //     200,000 (zeroed)
    int* cursor          = (int*)(ws + 115420480);             //     200,000 (zeroed)
    int* rowptr          = (int*)(ws + 115620480);             //     200,004
    int* bsum            = (int*)(ws + 115820484);             //         256
    int* boff            = (int*)(ws + 115820740);             //         256
    unsigned* srow       = (unsigned*)(ws + 115820996);        //   3,200,000
    // transient (dead after k_T/k_qk):
    unsigned short* xb   = (unsigned short*)(ws + 119021056);  //  12,800,000 (16B-aligned)
    unsigned short* Wt   = (unsigned short*)(ws + 131821056);  //     262,144

    hipMemsetAsync(ws + 115220480, 0, 400000, stream);  // deg|cursor

    k_cvt_x<<<3125, 256, 0, stream>>>(x, xb);
    k_cvt_wt<<<64, 256, 0, stream>>>(W, Wt);
    k_wqk<<<RR, 128, 0, stream>>>(W, qw, kw, Wqkt);
    k_qk<<<391, 256, 0, stream>>>(xb, Wqkt, QT, KT);
    k_T<<<3126, 256, 0, stream>>>(xb, Wt, T);
    k_hist<<<(EE + 255) / 256, 256, 0, stream>>>(ei, deg);
    k_scan1<<<49, 1024, 0, stream>>>(deg, rowptr, bsum);
    k_scan2<<<1, 64, 0, stream>>>(bsum, boff);
    k_scan3<<<49, 1024, 0, stream>>>(rowptr, boff);
    k_scatter<<<(EE + 255) / 256, 256, 0, stream>>>(ei, et, rowptr, cursor, srow);
    k_attagg<<<NN, 64, 0, stream>>>(rowptr, srow, QT, KT, T, bias, out);
}

// Round 9
// 312.926 us; speedup vs baseline: 3.2076x; 1.0108x over previous
//
#include <hip/hip_runtime.h>

#define NN 50000
#define EE 800000
#define INC 128
#define HCC 128
#define RR 8
#define HH 4
#define CHUNK 256

typedef __attribute__((ext_vector_type(8))) short bf16x8;
typedef __attribute__((ext_vector_type(4))) float f32x4;

// ---------- helpers ----------
static __device__ __forceinline__ unsigned f2b_rne(float f) {
    unsigned u = __float_as_uint(f);
    return (u + 0x7FFFu + ((u >> 16) & 1u)) >> 16;
}
static __device__ __forceinline__ float b2f(unsigned short s) {
    return __uint_as_float(((unsigned)s) << 16);
}

// T-row channel permutation: channel ch=(2*mg2+half)*16+kq*4+reg stored at
// ushort pos = mg2*32 + kq*8 + half*4 + reg. Makes k_T's store per lane a
// contiguous uint4 (64B per 4-lane group). k_attagg reads via the same map.

// ---------- prologue: x fp32 -> bf16 (row-major, feeds MFMA B-fragments) ----------
__global__ __launch_bounds__(256) void k_cvt_x(const float* __restrict__ x,
                                               unsigned short* __restrict__ xb) {
    int t = blockIdx.x * 256 + threadIdx.x;  // 800000 threads, 8 elems each
    const float4* p = (const float4*)x + t * 2;
    float4 v0 = p[0], v1 = p[1];
    uint4 pk;
    pk.x = f2b_rne(v0.x) | (f2b_rne(v0.y) << 16);
    pk.y = f2b_rne(v0.z) | (f2b_rne(v0.w) << 16);
    pk.z = f2b_rne(v1.x) | (f2b_rne(v1.y) << 16);
    pk.w = f2b_rne(v1.z) | (f2b_rne(v1.w) << 16);
    *((uint4*)xb + t) = pk;
}

// ---------- prologue: Wt[r][o][i] = bf16(W[r][i][o])  (A-fragment layout) ----------
__global__ __launch_bounds__(256) void k_cvt_wt(const float* __restrict__ W,
                                                unsigned short* __restrict__ Wt) {
    int t = blockIdx.x * 256 + threadIdx.x;  // 16384 threads
    int m = t & 127, kb = (t >> 7) & 15, r = t >> 11;
    unsigned short tmp[8];
#pragma unroll
    for (int j = 0; j < 8; ++j)
        tmp[j] = (unsigned short)f2b_rne(W[((r << 7) + (kb << 3) + j) * 128 + m]);
    uint4 pk;
    pk.x = tmp[0] | ((unsigned)tmp[1] << 16);
    pk.y = tmp[2] | ((unsigned)tmp[3] << 16);
    pk.z = tmp[4] | ((unsigned)tmp[5] << 16);
    pk.w = tmp[6] | ((unsigned)tmp[7] << 16);
    *(uint4*)(Wt + ((r << 7) + m) * 128 + (kb << 3)) = pk;
}

// ---------- K0: combined QK projection matrix, transposed bf16 ----------
__global__ __launch_bounds__(128) void k_wqk(const float* __restrict__ W,
                                             const float* __restrict__ qw,
                                             const float* __restrict__ kw,
                                             unsigned short* __restrict__ Wqkt) {
    int r = blockIdx.x, i = threadIdx.x;
    const float* wrow = W + (r * INC + i) * HCC;
    float aq0 = 0, aq1 = 0, aq2 = 0, aq3 = 0;
    float ak0 = 0, ak1 = 0, ak2 = 0, ak3 = 0;
    for (int o = 0; o < HCC; ++o) {
        float w = wrow[o];
        float4 qv = *(const float4*)(qw + o * 4);
        float4 kv = *(const float4*)(kw + o * 4);
        aq0 = fmaf(w, qv.x, aq0); aq1 = fmaf(w, qv.y, aq1);
        aq2 = fmaf(w, qv.z, aq2); aq3 = fmaf(w, qv.w, aq3);
        ak0 = fmaf(w, kv.x, ak0); ak1 = fmaf(w, kv.y, ak1);
        ak2 = fmaf(w, kv.z, ak2); ak3 = fmaf(w, kv.w, ak3);
    }
    int cq = r * 4, ck = 32 + r * 4;
    Wqkt[(cq + 0) * 128 + i] = (unsigned short)f2b_rne(aq0);
    Wqkt[(cq + 1) * 128 + i] = (unsigned short)f2b_rne(aq1);
    Wqkt[(cq + 2) * 128 + i] = (unsigned short)f2b_rne(aq2);
    Wqkt[(cq + 3) * 128 + i] = (unsigned short)f2b_rne(aq3);
    Wqkt[(ck + 0) * 128 + i] = (unsigned short)f2b_rne(ak0);
    Wqkt[(ck + 1) * 128 + i] = (unsigned short)f2b_rne(ak1);
    Wqkt[(ck + 2) * 128 + i] = (unsigned short)f2b_rne(ak2);
    Wqkt[(ck + 3) * 128 + i] = (unsigned short)f2b_rne(ak3);
}

// ---------- K1 (MFMA): [QT|KT] = x @ Wqk  (skinny GEMM, M=64 cols) ----------
__global__ __launch_bounds__(256) void k_qk(const unsigned short* __restrict__ xb,
                                            const unsigned short* __restrict__ Wqkt,
                                            float* __restrict__ QT,
                                            float* __restrict__ KT) {
    int wave = (blockIdx.x * 256 + threadIdx.x) >> 6;  // 2 node-tiles per wave
    int lane = threadIdx.x & 63;
    int nt0 = wave * 2, nt1 = nt0 + 1;
    if (nt0 >= 3125) return;
    bool has1 = nt1 < 3125;
    int ln = lane & 15, kq = lane >> 4;

    const unsigned short* x0 = xb + (nt0 * 16 + ln) * 128 + kq * 8;
    const unsigned short* x1 = xb + ((has1 ? nt1 : nt0) * 16 + ln) * 128 + kq * 8;
    bf16x8 b0[4], b1[4];
#pragma unroll
    for (int ks = 0; ks < 4; ++ks) {
        b0[ks] = *(const bf16x8*)(x0 + ks * 32);
        b1[ks] = *(const bf16x8*)(x1 + ks * 32);
    }
    const unsigned short* ab = Wqkt + ln * 128 + kq * 8;
#pragma unroll
    for (int mg = 0; mg < 4; ++mg) {
        f32x4 acc0 = {0.f, 0.f, 0.f, 0.f};
        f32x4 acc1 = {0.f, 0.f, 0.f, 0.f};
#pragma unroll
        for (int ks = 0; ks < 4; ++ks) {
            bf16x8 a = *(const bf16x8*)(ab + mg * 2048 + ks * 32);
            acc0 = __builtin_amdgcn_mfma_f32_16x16x32_bf16(a, b0[ks], acc0, 0, 0, 0);
            acc1 = __builtin_amdgcn_mfma_f32_16x16x32_bf16(a, b1[ks], acc1, 0, 0, 0);
        }
        float* base = (mg < 2) ? QT : KT;
        int rr = (mg & 1) * 4 + kq;  // relation index
        *(f32x4*)(base + ((nt0 * 16 + ln) * 8 + rr) * 4) = acc0;
        if (has1) *(f32x4*)(base + ((nt1 * 16 + ln) * 8 + rr) * 4) = acc1;
    }
}

// ---------- K2 (MFMA): T[n,r,:] = x[n,:] @ W_r (permuted row layout) ----------
// Per mg-pair (mg2): lane packs even-mg 4ch + odd-mg 4ch into one uint4 ->
// 4-lane ln-group writes 64B contiguous (no HBM write amplification).
__global__ __launch_bounds__(256) void k_T(const unsigned short* __restrict__ xb,
                                           const unsigned short* __restrict__ Wt,
                                           unsigned short* __restrict__ T) {
    int wave = (blockIdx.x * 256 + threadIdx.x) >> 6;  // 0..12503
    int lane = threadIdx.x & 63;
    int r = wave & 7;
    int p = wave >> 3;          // 0..1562
    int nt0 = p * 2, nt1 = nt0 + 1;
    bool has1 = nt1 < 3125;
    int ln = lane & 15, kq = lane >> 4;

    const unsigned short* x0 = xb + (nt0 * 16 + ln) * 128 + kq * 8;
    const unsigned short* x1 = xb + ((has1 ? nt1 : nt0) * 16 + ln) * 128 + kq * 8;
    bf16x8 b0[4], b1[4];
#pragma unroll
    for (int ks = 0; ks < 4; ++ks) {
        b0[ks] = *(const bf16x8*)(x0 + ks * 32);
        b1[ks] = *(const bf16x8*)(x1 + ks * 32);
    }
    const unsigned short* wb = Wt + (r * 128 + ln) * 128 + kq * 8;
#pragma unroll
    for (int mg2 = 0; mg2 < 4; ++mg2) {
        f32x4 e0 = {0.f, 0.f, 0.f, 0.f};  // even mg, tile0
        f32x4 o0 = {0.f, 0.f, 0.f, 0.f};  // odd  mg, tile0
        f32x4 e1 = {0.f, 0.f, 0.f, 0.f};
        f32x4 o1 = {0.f, 0.f, 0.f, 0.f};
#pragma unroll
        for (int ks = 0; ks < 4; ++ks) {
            bf16x8 ae = *(const bf16x8*)(wb + (2 * mg2) * 2048 + ks * 32);
            bf16x8 ao = *(const bf16x8*)(wb + (2 * mg2 + 1) * 2048 + ks * 32);
            e0 = __builtin_amdgcn_mfma_f32_16x16x32_bf16(ae, b0[ks], e0, 0, 0, 0);
            o0 = __builtin_amdgcn_mfma_f32_16x16x32_bf16(ao, b0[ks], o0, 0, 0, 0);
            e1 = __builtin_amdgcn_mfma_f32_16x16x32_bf16(ae, b1[ks], e1, 0, 0, 0);
            o1 = __builtin_amdgcn_mfma_f32_16x16x32_bf16(ao, b1[ks], o1, 0, 0, 0);
        }
        uint4 pk0, pk1;
        pk0.x = f2b_rne(e0[0]) | (f2b_rne(e0[1]) << 16);
        pk0.y = f2b_rne(e0[2]) | (f2b_rne(e0[3]) << 16);
        pk0.z = f2b_rne(o0[0]) | (f2b_rne(o0[1]) << 16);
        pk0.w = f2b_rne(o0[2]) | (f2b_rne(o0[3]) << 16);
        pk1.x = f2b_rne(e1[0]) | (f2b_rne(e1[1]) << 16);
        pk1.y = f2b_rne(e1[2]) | (f2b_rne(e1[3]) << 16);
        pk1.z = f2b_rne(o1[0]) | (f2b_rne(o1[1]) << 16);
        pk1.w = f2b_rne(o1[2]) | (f2b_rne(o1[3]) << 16);
        int pos = mg2 * 32 + kq * 8;  // ushort offset in permuted row
        *(uint4*)(T + ((nt0 * 16 + ln) * 8 + r) * 128 + pos) = pk0;
        if (has1) *(uint4*)(T + ((nt1 * 16 + ln) * 8 + r) * 128 + pos) = pk1;
    }
}

// ---------- CSR build ----------
__global__ __launch_bounds__(256) void k_hist(const int* __restrict__ ei,
                                              int* __restrict__ deg) {
    int e = blockIdx.x * 256 + threadIdx.x;
    if (e >= EE) return;
    atomicAdd(&deg[ei[EE + e]], 1);
}

__global__ __launch_bounds__(1024) void k_scan1(const int* __restrict__ deg,
                                                int* __restrict__ rowptr,
                                                int* __restrict__ bsum) {
    __shared__ int s[1024];
    int tid = threadIdx.x;
    int g = blockIdx.x * 1024 + tid;
    int v = (g < NN) ? deg[g] : 0;
    s[tid] = v;
    __syncthreads();
    for (int off = 1; off < 1024; off <<= 1) {
        int t = (tid >= off) ? s[tid - off] : 0;
        __syncthreads();
        s[tid] += t;
        __syncthreads();
    }
    if (g < NN) rowptr[g + 1] = s[tid];  // chunk-local inclusive
    if (tid == 1023) bsum[blockIdx.x] = s[1023];
}

__global__ void k_scan2(const int* __restrict__ bsum, int* __restrict__ boff) {
    int tid = threadIdx.x;  // 64 = 1 wave
    const int NB = (NN + 1023) / 1024;  // 49
    int v = (tid < NB) ? bsum[tid] : 0;
    int orig = v;
    for (int off = 1; off < 64; off <<= 1) {
        int t = __shfl_up(v, off);
        if (tid >= off) v += t;
    }
    if (tid < NB) boff[tid] = v - orig;  // exclusive
}

__global__ __launch_bounds__(1024) void k_scan3(int* __restrict__ rowptr,
                                                const int* __restrict__ boff) {
    int tid = threadIdx.x;
    int g = blockIdx.x * 1024 + tid;
    if (g == 0) rowptr[0] = 0;
    if (g < NN) rowptr[g + 1] += boff[blockIdx.x];
}

__global__ __launch_bounds__(256) void k_scatter(const int* __restrict__ ei,
                                                 const int* __restrict__ et,
                                                 const int* __restrict__ rowptr,
                                                 int* __restrict__ cursor,
                                                 unsigned* __restrict__ srow) {
    int e = blockIdx.x * 256 + threadIdx.x;
    if (e >= EE) return;
    int src = ei[e], dst = ei[EE + e], r = et[e];
    int pos = rowptr[dst] + atomicAdd(&cursor[dst], 1);
    srow[pos] = (unsigned)(src * RR + r);  // T row index (src*8+r)
}

// ---------- fused attention + aggregate: one wave per node, flash-style ----------
__global__ __launch_bounds__(64) void k_attagg(const int* __restrict__ rowptr,
                                               const unsigned* __restrict__ srow,
                                               const float* __restrict__ QT,
                                               const float* __restrict__ KT,
                                               const unsigned short* __restrict__ T,
                                               const float* __restrict__ bias,
                                               float* __restrict__ out) {
    __shared__ float als[CHUNK * 4];
    __shared__ unsigned srw[CHUNK];
    __shared__ float qs[32];
    const int n = blockIdx.x;
    const int lane = threadIdx.x;
    const int h = lane >> 4;       // head for channels 2*lane, 2*lane+1
    const int c = lane * 2;
    // permuted T-row offset for channel pair (c, c+1)
    const int mgv = c >> 4, kqv = (c >> 2) & 3, regv = c & 3;
    const int posu = (mgv >> 1) * 32 + kqv * 8 + (mgv & 1) * 4 + regv;
    const int beg = rowptr[n], end = rowptr[n + 1];

    if (lane < 32) qs[lane] = QT[n * 32 + lane];
    __syncthreads();

    float m0 = -3.0e38f, m1 = -3.0e38f, m2 = -3.0e38f, m3 = -3.0e38f;
    float d0 = 0.f, d1 = 0.f, d2 = 0.f, d3 = 0.f;
    float accx = 0.f, accy = 0.f;

    for (int j0 = beg; j0 < end; j0 += CHUNK) {
        const int cnt = min(CHUNK, end - j0);
        // --- phase A: edge-parallel logits + local max ---
        float lm0 = -3.0e38f, lm1 = -3.0e38f, lm2 = -3.0e38f, lm3 = -3.0e38f;
        for (int jj = lane; jj < cnt; jj += 64) {
            unsigned sr = srow[j0 + jj];
            srw[jj] = sr;
            int r = sr & 7;
            float4 kj = *(const float4*)(KT + sr * 4);
            float a0 = qs[r * 4 + 0] + kj.x;
            float a1 = qs[r * 4 + 1] + kj.y;
            float a2 = qs[r * 4 + 2] + kj.z;
            float a3 = qs[r * 4 + 3] + kj.w;
            a0 = a0 > 0.f ? a0 : 0.2f * a0;
            a1 = a1 > 0.f ? a1 : 0.2f * a1;
            a2 = a2 > 0.f ? a2 : 0.2f * a2;
            a3 = a3 > 0.f ? a3 : 0.2f * a3;
            als[jj * 4 + 0] = a0; als[jj * 4 + 1] = a1;
            als[jj * 4 + 2] = a2; als[jj * 4 + 3] = a3;
            lm0 = fmaxf(lm0, a0); lm1 = fmaxf(lm1, a1);
            lm2 = fmaxf(lm2, a2); lm3 = fmaxf(lm3, a3);
        }
        __syncthreads();
        // --- wave max reduce ---
#pragma unroll
        for (int off = 1; off < 64; off <<= 1) {
            lm0 = fmaxf(lm0, __shfl_xor(lm0, off));
            lm1 = fmaxf(lm1, __shfl_xor(lm1, off));
            lm2 = fmaxf(lm2, __shfl_xor(lm2, off));
            lm3 = fmaxf(lm3, __shfl_xor(lm3, off));
        }
        // --- online rescale ---
        float nm0 = fmaxf(m0, lm0), nm1 = fmaxf(m1, lm1);
        float nm2 = fmaxf(m2, lm2), nm3 = fmaxf(m3, lm3);
        float s0 = expf(m0 - nm0), s1 = expf(m1 - nm1);
        float s2 = expf(m2 - nm2), s3 = expf(m3 - nm3);
        d0 *= s0; d1 *= s1; d2 *= s2; d3 *= s3;
        float sh = h == 0 ? s0 : h == 1 ? s1 : h == 2 ? s2 : s3;
        accx *= sh; accy *= sh;
        m0 = nm0; m1 = nm1; m2 = nm2; m3 = nm3;
        // --- phase D: exp + denom partial ---
        float p0 = 0.f, p1 = 0.f, p2 = 0.f, p3 = 0.f;
        for (int jj = lane; jj < cnt; jj += 64) {
            float e0 = expf(als[jj * 4 + 0] - m0);
            float e1 = expf(als[jj * 4 + 1] - m1);
            float e2 = expf(als[jj * 4 + 2] - m2);
            float e3 = expf(als[jj * 4 + 3] - m3);
            als[jj * 4 + 0] = e0; als[jj * 4 + 1] = e1;
            als[jj * 4 + 2] = e2; als[jj * 4 + 3] = e3;
            p0 += e0; p1 += e1; p2 += e2; p3 += e3;
        }
#pragma unroll
        for (int off = 1; off < 64; off <<= 1) {
            p0 += __shfl_xor(p0, off);
            p1 += __shfl_xor(p1, off);
            p2 += __shfl_xor(p2, off);
            p3 += __shfl_xor(p3, off);
        }
        d0 += p0; d1 += p1; d2 += p2; d3 += p3;
        __syncthreads();
        // --- phase E: channel-parallel weighted T accumulate (permuted read) ---
        for (int jj = 0; jj < cnt; ++jj) {
            float w = als[jj * 4 + h];
            unsigned pk = *(const unsigned*)(T + srw[jj] * 128 + posu);
            accx = fmaf(w, b2f((unsigned short)(pk & 0xFFFF)), accx);
            accy = fmaf(w, b2f((unsigned short)(pk >> 16)), accy);
        }
        __syncthreads();
    }
    float dh = h == 0 ? d0 : h == 1 ? d1 : h == 2 ? d2 : d3;
    float inv = 1.f / (dh + 1e-16f);
    out[n * 128 + c] = accx * inv + bias[c];
    out[n * 128 + c + 1] = accy * inv + bias[c + 1];
}

extern "C" void kernel_launch(void* const* d_in, const int* in_sizes, int n_in,
                              void* d_out, int out_size, void* d_ws, size_t ws_size,
                              hipStream_t stream) {
    const float* x    = (const float*)d_in[0];
    const int*   ei   = (const int*)d_in[1];
    const int*   et   = (const int*)d_in[2];
    const float* W    = (const float*)d_in[3];
    const float* qw   = (const float*)d_in[4];
    const float* kw   = (const float*)d_in[5];
    const float* bias = (const float*)d_in[6];
    float* out = (float*)d_out;
    char* ws = (char*)d_ws;

    // workspace layout (bytes) — total ~132 MB
    unsigned short* T    = (unsigned short*)(ws + 0);          // 102,400,000
    float* QT            = (float*)(ws + 102400000);           //   6,400,000
    float* KT            = (float*)(ws + 108800000);           //   6,400,000
    unsigned short* Wqkt = (unsigned short*)(ws + 115200000);  //      16,384
    int* deg             = (int*)(ws + 115220480);             //     200,000 (zeroed)
    int* cursor          = (int*)(ws + 115420480);             //     200,000 (zeroed)
    int* rowptr          = (int*)(ws + 115620480);             //     200,004
    int* bsum            = (int*)(ws + 115820484);             //         256
    int* boff            = (int*)(ws + 115820740);             //         256
    unsigned* srow       = (unsigned*)(ws + 115820996);        //   3,200,000
    // transient (dead after k_T/k_qk):
    unsigned short* xb   = (unsigned short*)(ws + 119021056);  //  12,800,000 (16B-aligned)
    unsigned short* Wt   = (unsigned short*)(ws + 131821056);  //     262,144

    hipMemsetAsync(ws + 115220480, 0, 400000, stream);  // deg|cursor

    k_cvt_x<<<3125, 256, 0, stream>>>(x, xb);
    k_cvt_wt<<<64, 256, 0, stream>>>(W, Wt);
    k_wqk<<<RR, 128, 0, stream>>>(W, qw, kw, Wqkt);
    k_qk<<<391, 256, 0, stream>>>(xb, Wqkt, QT, KT);
    k_T<<<3126, 256, 0, stream>>>(xb, Wt, T);
    k_hist<<<(EE + 255) / 256, 256, 0, stream>>>(ei, deg);
    k_scan1<<<49, 1024, 0, stream>>>(deg, rowptr, bsum);
    k_scan2<<<1, 64, 0, stream>>>(bsum, boff);
    k_scan3<<<49, 1024, 0, stream>>>(rowptr, boff);
    k_scatter<<<(EE + 255) / 256, 256, 0, stream>>>(ei, et, rowptr, cursor, srow);
    k_attagg<<<NN, 64, 0, stream>>>(rowptr, srow, QT, KT, T, bias, out);
}

// Round 10
// 311.335 us; speedup vs baseline: 3.2240x; 1.0051x over previous
//
#include <hip/hip_runtime.h>

#define NN 50000
#define EE 800000
#define INC 128
#define HCC 128
#define RR 8
#define HH 4
#define CHUNK 256

typedef __attribute__((ext_vector_type(8))) short bf16x8;
typedef __attribute__((ext_vector_type(4))) float f32x4;

// ---------- helpers ----------
static __device__ __forceinline__ unsigned f2b_rne(float f) {
    unsigned u = __float_as_uint(f);
    return (u + 0x7FFFu + ((u >> 16) & 1u)) >> 16;
}
static __device__ __forceinline__ float b2f(unsigned short s) {
    return __uint_as_float(((unsigned)s) << 16);
}

// T-row channel permutation: channel ch=(2*mg2+half)*16+kq*4+reg stored at
// ushort pos = mg2*32 + kq*8 + half*4 + reg. Makes k_T's store per lane a
// contiguous uint4 (64B per 4-lane group). k_attagg reads via the same map.

// ---------- prologue: x fp32 -> bf16 (row-major, feeds MFMA B-fragments) ----------
__global__ __launch_bounds__(256) void k_cvt_x(const float* __restrict__ x,
                                               unsigned short* __restrict__ xb) {
    int t = blockIdx.x * 256 + threadIdx.x;  // 800000 threads, 8 elems each
    const float4* p = (const float4*)x + t * 2;
    float4 v0 = p[0], v1 = p[1];
    uint4 pk;
    pk.x = f2b_rne(v0.x) | (f2b_rne(v0.y) << 16);
    pk.y = f2b_rne(v0.z) | (f2b_rne(v0.w) << 16);
    pk.z = f2b_rne(v1.x) | (f2b_rne(v1.y) << 16);
    pk.w = f2b_rne(v1.z) | (f2b_rne(v1.w) << 16);
    *((uint4*)xb + t) = pk;
}

// ---------- prologue: Wt[r][o][i] = bf16(W[r][i][o])  (A-fragment layout) ----------
__global__ __launch_bounds__(256) void k_cvt_wt(const float* __restrict__ W,
                                                unsigned short* __restrict__ Wt) {
    int t = blockIdx.x * 256 + threadIdx.x;  // 16384 threads
    int m = t & 127, kb = (t >> 7) & 15, r = t >> 11;
    unsigned short tmp[8];
#pragma unroll
    for (int j = 0; j < 8; ++j)
        tmp[j] = (unsigned short)f2b_rne(W[((r << 7) + (kb << 3) + j) * 128 + m]);
    uint4 pk;
    pk.x = tmp[0] | ((unsigned)tmp[1] << 16);
    pk.y = tmp[2] | ((unsigned)tmp[3] << 16);
    pk.z = tmp[4] | ((unsigned)tmp[5] << 16);
    pk.w = tmp[6] | ((unsigned)tmp[7] << 16);
    *(uint4*)(Wt + ((r << 7) + m) * 128 + (kb << 3)) = pk;
}

// ---------- K0: combined QK projection matrix, transposed bf16 ----------
__global__ __launch_bounds__(128) void k_wqk(const float* __restrict__ W,
                                             const float* __restrict__ qw,
                                             const float* __restrict__ kw,
                                             unsigned short* __restrict__ Wqkt) {
    int r = blockIdx.x, i = threadIdx.x;
    const float* wrow = W + (r * INC + i) * HCC;
    float aq0 = 0, aq1 = 0, aq2 = 0, aq3 = 0;
    float ak0 = 0, ak1 = 0, ak2 = 0, ak3 = 0;
    for (int o = 0; o < HCC; ++o) {
        float w = wrow[o];
        float4 qv = *(const float4*)(qw + o * 4);
        float4 kv = *(const float4*)(kw + o * 4);
        aq0 = fmaf(w, qv.x, aq0); aq1 = fmaf(w, qv.y, aq1);
        aq2 = fmaf(w, qv.z, aq2); aq3 = fmaf(w, qv.w, aq3);
        ak0 = fmaf(w, kv.x, ak0); ak1 = fmaf(w, kv.y, ak1);
        ak2 = fmaf(w, kv.z, ak2); ak3 = fmaf(w, kv.w, ak3);
    }
    int cq = r * 4, ck = 32 + r * 4;
    Wqkt[(cq + 0) * 128 + i] = (unsigned short)f2b_rne(aq0);
    Wqkt[(cq + 1) * 128 + i] = (unsigned short)f2b_rne(aq1);
    Wqkt[(cq + 2) * 128 + i] = (unsigned short)f2b_rne(aq2);
    Wqkt[(cq + 3) * 128 + i] = (unsigned short)f2b_rne(aq3);
    Wqkt[(ck + 0) * 128 + i] = (unsigned short)f2b_rne(ak0);
    Wqkt[(ck + 1) * 128 + i] = (unsigned short)f2b_rne(ak1);
    Wqkt[(ck + 2) * 128 + i] = (unsigned short)f2b_rne(ak2);
    Wqkt[(ck + 3) * 128 + i] = (unsigned short)f2b_rne(ak3);
}

// ---------- K1 (MFMA): [QT|KT] = x @ Wqk  (skinny GEMM, M=64 cols) ----------
// __launch_bounds__(256,4): 128-VGPR cap so B-fragments stay resident
// (at the default budget the compiler allocated 32 VGPR and serialized loads).
__global__ __launch_bounds__(256, 4) void k_qk(const unsigned short* __restrict__ xb,
                                               const unsigned short* __restrict__ Wqkt,
                                               float* __restrict__ QT,
                                               float* __restrict__ KT) {
    int wave = (blockIdx.x * 256 + threadIdx.x) >> 6;  // 2 node-tiles per wave
    int lane = threadIdx.x & 63;
    int nt0 = wave * 2, nt1 = nt0 + 1;
    if (nt0 >= 3125) return;
    bool has1 = nt1 < 3125;
    int ln = lane & 15, kq = lane >> 4;

    const unsigned short* x0 = xb + (nt0 * 16 + ln) * 128 + kq * 8;
    const unsigned short* x1 = xb + ((has1 ? nt1 : nt0) * 16 + ln) * 128 + kq * 8;
    bf16x8 b0[4], b1[4];
#pragma unroll
    for (int ks = 0; ks < 4; ++ks) {
        b0[ks] = *(const bf16x8*)(x0 + ks * 32);
        b1[ks] = *(const bf16x8*)(x1 + ks * 32);
    }
    const unsigned short* ab = Wqkt + ln * 128 + kq * 8;
#pragma unroll
    for (int mg = 0; mg < 4; ++mg) {
        f32x4 acc0 = {0.f, 0.f, 0.f, 0.f};
        f32x4 acc1 = {0.f, 0.f, 0.f, 0.f};
#pragma unroll
        for (int ks = 0; ks < 4; ++ks) {
            bf16x8 a = *(const bf16x8*)(ab + mg * 2048 + ks * 32);
            acc0 = __builtin_amdgcn_mfma_f32_16x16x32_bf16(a, b0[ks], acc0, 0, 0, 0);
            acc1 = __builtin_amdgcn_mfma_f32_16x16x32_bf16(a, b1[ks], acc1, 0, 0, 0);
        }
        float* base = (mg < 2) ? QT : KT;
        int rr = (mg & 1) * 4 + kq;  // relation index
        *(f32x4*)(base + ((nt0 * 16 + ln) * 8 + rr) * 4) = acc0;
        if (has1) *(f32x4*)(base + ((nt1 * 16 + ln) * 8 + rr) * 4) = acc1;
    }
}

// ---------- K2 (MFMA): T[n,r,:] = x[n,:] @ W_r (permuted row layout) ----------
// Per mg-pair (mg2): lane packs even-mg 4ch + odd-mg 4ch into one uint4 ->
// 4-lane ln-group writes 64B contiguous (no HBM write amplification).
// __launch_bounds__(256,4): 128-VGPR cap — the working set (32 B-frag + 16 acc
// + addrs) needs ~64+; the default budget gave 40 VGPR and load-serialized.
__global__ __launch_bounds__(256, 4) void k_T(const unsigned short* __restrict__ xb,
                                              const unsigned short* __restrict__ Wt,
                                              unsigned short* __restrict__ T) {
    int wave = (blockIdx.x * 256 + threadIdx.x) >> 6;  // 0..12503
    int lane = threadIdx.x & 63;
    int r = wave & 7;
    int p = wave >> 3;          // 0..1562
    int nt0 = p * 2, nt1 = nt0 + 1;
    bool has1 = nt1 < 3125;
    int ln = lane & 15, kq = lane >> 4;

    const unsigned short* x0 = xb + (nt0 * 16 + ln) * 128 + kq * 8;
    const unsigned short* x1 = xb + ((has1 ? nt1 : nt0) * 16 + ln) * 128 + kq * 8;
    bf16x8 b0[4], b1[4];
#pragma unroll
    for (int ks = 0; ks < 4; ++ks) {
        b0[ks] = *(const bf16x8*)(x0 + ks * 32);
        b1[ks] = *(const bf16x8*)(x1 + ks * 32);
    }
    const unsigned short* wb = Wt + (r * 128 + ln) * 128 + kq * 8;
#pragma unroll
    for (int mg2 = 0; mg2 < 4; ++mg2) {
        f32x4 e0 = {0.f, 0.f, 0.f, 0.f};  // even mg, tile0
        f32x4 o0 = {0.f, 0.f, 0.f, 0.f};  // odd  mg, tile0
        f32x4 e1 = {0.f, 0.f, 0.f, 0.f};
        f32x4 o1 = {0.f, 0.f, 0.f, 0.f};
#pragma unroll
        for (int ks = 0; ks < 4; ++ks) {
            bf16x8 ae = *(const bf16x8*)(wb + (2 * mg2) * 2048 + ks * 32);
            bf16x8 ao = *(const bf16x8*)(wb + (2 * mg2 + 1) * 2048 + ks * 32);
            e0 = __builtin_amdgcn_mfma_f32_16x16x32_bf16(ae, b0[ks], e0, 0, 0, 0);
            o0 = __builtin_amdgcn_mfma_f32_16x16x32_bf16(ao, b0[ks], o0, 0, 0, 0);
            e1 = __builtin_amdgcn_mfma_f32_16x16x32_bf16(ae, b1[ks], e1, 0, 0, 0);
            o1 = __builtin_amdgcn_mfma_f32_16x16x32_bf16(ao, b1[ks], o1, 0, 0, 0);
        }
        uint4 pk0, pk1;
        pk0.x = f2b_rne(e0[0]) | (f2b_rne(e0[1]) << 16);
        pk0.y = f2b_rne(e0[2]) | (f2b_rne(e0[3]) << 16);
        pk0.z = f2b_rne(o0[0]) | (f2b_rne(o0[1]) << 16);
        pk0.w = f2b_rne(o0[2]) | (f2b_rne(o0[3]) << 16);
        pk1.x = f2b_rne(e1[0]) | (f2b_rne(e1[1]) << 16);
        pk1.y = f2b_rne(e1[2]) | (f2b_rne(e1[3]) << 16);
        pk1.z = f2b_rne(o1[0]) | (f2b_rne(o1[1]) << 16);
        pk1.w = f2b_rne(o1[2]) | (f2b_rne(o1[3]) << 16);
        int pos = mg2 * 32 + kq * 8;  // ushort offset in permuted row
        *(uint4*)(T + ((nt0 * 16 + ln) * 8 + r) * 128 + pos) = pk0;
        if (has1) *(uint4*)(T + ((nt1 * 16 + ln) * 8 + r) * 128 + pos) = pk1;
    }
}

// ---------- CSR build ----------
__global__ __launch_bounds__(256) void k_hist(const int* __restrict__ ei,
                                              int* __restrict__ deg) {
    int e = blockIdx.x * 256 + threadIdx.x;
    if (e >= EE) return;
    atomicAdd(&deg[ei[EE + e]], 1);
}

__global__ __launch_bounds__(1024) void k_scan1(const int* __restrict__ deg,
                                                int* __restrict__ rowptr,
                                                int* __restrict__ bsum) {
    __shared__ int s[1024];
    int tid = threadIdx.x;
    int g = blockIdx.x * 1024 + tid;
    int v = (g < NN) ? deg[g] : 0;
    s[tid] = v;
    __syncthreads();
    for (int off = 1; off < 1024; off <<= 1) {
        int t = (tid >= off) ? s[tid - off] : 0;
        __syncthreads();
        s[tid] += t;
        __syncthreads();
    }
    if (g < NN) rowptr[g + 1] = s[tid];  // chunk-local inclusive
    if (tid == 1023) bsum[blockIdx.x] = s[1023];
}

__global__ void k_scan2(const int* __restrict__ bsum, int* __restrict__ boff) {
    int tid = threadIdx.x;  // 64 = 1 wave
    const int NB = (NN + 1023) / 1024;  // 49
    int v = (tid < NB) ? bsum[tid] : 0;
    int orig = v;
    for (int off = 1; off < 64; off <<= 1) {
        int t = __shfl_up(v, off);
        if (tid >= off) v += t;
    }
    if (tid < NB) boff[tid] = v - orig;  // exclusive
}

__global__ __launch_bounds__(1024) void k_scan3(int* __restrict__ rowptr,
                                                const int* __restrict__ boff) {
    int tid = threadIdx.x;
    int g = blockIdx.x * 1024 + tid;
    if (g == 0) rowptr[0] = 0;
    if (g < NN) rowptr[g + 1] += boff[blockIdx.x];
}

__global__ __launch_bounds__(256) void k_scatter(const int* __restrict__ ei,
                                                 const int* __restrict__ et,
                                                 const int* __restrict__ rowptr,
                                                 int* __restrict__ cursor,
                                                 unsigned* __restrict__ srow) {
    int e = blockIdx.x * 256 + threadIdx.x;
    if (e >= EE) return;
    int src = ei[e], dst = ei[EE + e], r = et[e];
    int pos = rowptr[dst] + atomicAdd(&cursor[dst], 1);
    srow[pos] = (unsigned)(src * RR + r);  // T row index (src*8+r)
}

// ---------- fused attention + aggregate: one wave per node, flash-style ----------
__global__ __launch_bounds__(64) void k_attagg(const int* __restrict__ rowptr,
                                               const unsigned* __restrict__ srow,
                                               const float* __restrict__ QT,
                                               const float* __restrict__ KT,
                                               const unsigned short* __restrict__ T,
                                               const float* __restrict__ bias,
                                               float* __restrict__ out) {
    __shared__ float als[CHUNK * 4];
    __shared__ unsigned srw[CHUNK];
    __shared__ float qs[32];
    const int n = blockIdx.x;
    const int lane = threadIdx.x;
    const int h = lane >> 4;       // head for channels 2*lane, 2*lane+1
    const int c = lane * 2;
    // permuted T-row offset for channel pair (c, c+1)
    const int mgv = c >> 4, kqv = (c >> 2) & 3, regv = c & 3;
    const int posu = (mgv >> 1) * 32 + kqv * 8 + (mgv & 1) * 4 + regv;
    const int beg = rowptr[n], end = rowptr[n + 1];

    if (lane < 32) qs[lane] = QT[n * 32 + lane];
    __syncthreads();

    float m0 = -3.0e38f, m1 = -3.0e38f, m2 = -3.0e38f, m3 = -3.0e38f;
    float d0 = 0.f, d1 = 0.f, d2 = 0.f, d3 = 0.f;
    float accx = 0.f, accy = 0.f;

    for (int j0 = beg; j0 < end; j0 += CHUNK) {
        const int cnt = min(CHUNK, end - j0);
        // --- phase A: edge-parallel logits + local max ---
        float lm0 = -3.0e38f, lm1 = -3.0e38f, lm2 = -3.0e38f, lm3 = -3.0e38f;
        for (int jj = lane; jj < cnt; jj += 64) {
            unsigned sr = srow[j0 + jj];
            srw[jj] = sr;
            int r = sr & 7;
            float4 kj = *(const float4*)(KT + sr * 4);
            float a0 = qs[r * 4 + 0] + kj.x;
            float a1 = qs[r * 4 + 1] + kj.y;
            float a2 = qs[r * 4 + 2] + kj.z;
            float a3 = qs[r * 4 + 3] + kj.w;
            a0 = a0 > 0.f ? a0 : 0.2f * a0;
            a1 = a1 > 0.f ? a1 : 0.2f * a1;
            a2 = a2 > 0.f ? a2 : 0.2f * a2;
            a3 = a3 > 0.f ? a3 : 0.2f * a3;
            als[jj * 4 + 0] = a0; als[jj * 4 + 1] = a1;
            als[jj * 4 + 2] = a2; als[jj * 4 + 3] = a3;
            lm0 = fmaxf(lm0, a0); lm1 = fmaxf(lm1, a1);
            lm2 = fmaxf(lm2, a2); lm3 = fmaxf(lm3, a3);
        }
        __syncthreads();
        // --- wave max reduce ---
#pragma unroll
        for (int off = 1; off < 64; off <<= 1) {
            lm0 = fmaxf(lm0, __shfl_xor(lm0, off));
            lm1 = fmaxf(lm1, __shfl_xor(lm1, off));
            lm2 = fmaxf(lm2, __shfl_xor(lm2, off));
            lm3 = fmaxf(lm3, __shfl_xor(lm3, off));
        }
        // --- online rescale ---
        float nm0 = fmaxf(m0, lm0), nm1 = fmaxf(m1, lm1);
        float nm2 = fmaxf(m2, lm2), nm3 = fmaxf(m3, lm3);
        float s0 = expf(m0 - nm0), s1 = expf(m1 - nm1);
        float s2 = expf(m2 - nm2), s3 = expf(m3 - nm3);
        d0 *= s0; d1 *= s1; d2 *= s2; d3 *= s3;
        float sh = h == 0 ? s0 : h == 1 ? s1 : h == 2 ? s2 : s3;
        accx *= sh; accy *= sh;
        m0 = nm0; m1 = nm1; m2 = nm2; m3 = nm3;
        // --- phase D: exp + denom partial ---
        float p0 = 0.f, p1 = 0.f, p2 = 0.f, p3 = 0.f;
        for (int jj = lane; jj < cnt; jj += 64) {
            float e0 = expf(als[jj * 4 + 0] - m0);
            float e1 = expf(als[jj * 4 + 1] - m1);
            float e2 = expf(als[jj * 4 + 2] - m2);
            float e3 = expf(als[jj * 4 + 3] - m3);
            als[jj * 4 + 0] = e0; als[jj * 4 + 1] = e1;
            als[jj * 4 + 2] = e2; als[jj * 4 + 3] = e3;
            p0 += e0; p1 += e1; p2 += e2; p3 += e3;
        }
#pragma unroll
        for (int off = 1; off < 64; off <<= 1) {
            p0 += __shfl_xor(p0, off);
            p1 += __shfl_xor(p1, off);
            p2 += __shfl_xor(p2, off);
            p3 += __shfl_xor(p3, off);
        }
        d0 += p0; d1 += p1; d2 += p2; d3 += p3;
        __syncthreads();
        // --- phase E: channel-parallel weighted T accumulate (permuted read) ---
        for (int jj = 0; jj < cnt; ++jj) {
            float w = als[jj * 4 + h];
            unsigned pk = *(const unsigned*)(T + srw[jj] * 128 + posu);
            accx = fmaf(w, b2f((unsigned short)(pk & 0xFFFF)), accx);
            accy = fmaf(w, b2f((unsigned short)(pk >> 16)), accy);
        }
        __syncthreads();
    }
    float dh = h == 0 ? d0 : h == 1 ? d1 : h == 2 ? d2 : d3;
    float inv = 1.f / (dh + 1e-16f);
    out[n * 128 + c] = accx * inv + bias[c];
    out[n * 128 + c + 1] = accy * inv + bias[c + 1];
}

extern "C" void kernel_launch(void* const* d_in, const int* in_sizes, int n_in,
                              void* d_out, int out_size, void* d_ws, size_t ws_size,
                              hipStream_t stream) {
    const float* x    = (const float*)d_in[0];
    const int*   ei   = (const int*)d_in[1];
    const int*   et   = (const int*)d_in[2];
    const float* W    = (const float*)d_in[3];
    const float* qw   = (const float*)d_in[4];
    const float* kw   = (const float*)d_in[5];
    const float* bias = (const float*)d_in[6];
    float* out = (float*)d_out;
    char* ws = (char*)d_ws;

    // workspace layout (bytes) — total ~132 MB
    unsigned short* T    = (unsigned short*)(ws + 0);          // 102,400,000
    float* QT            = (float*)(ws + 102400000);           //   6,400,000
    float* KT            = (float*)(ws + 108800000);           //   6,400,000
    unsigned short* Wqkt = (unsigned short*)(ws + 115200000);  //      16,384
    int* deg             = (int*)(ws + 115220480);             //     200,000 (zeroed)
    int* cursor          = (int*)(ws + 115420480);             //     200,000 (zeroed)
    int* rowptr          = (int*)(ws + 115620480);             //     200,004
    int* bsum            = (int*)(ws + 115820484);             //         256
    int* boff            = (int*)(ws + 115820740);             //         256
    unsigned* srow       = (unsigned*)(ws + 115820996);        //   3,200,000
    // transient (dead after k_T/k_qk):
    unsigned short* xb   = (unsigned short*)(ws + 119021056);  //  12,800,000 (16B-aligned)
    unsigned short* Wt   = (unsigned short*)(ws + 131821056);  //     262,144

    hipMemsetAsync(ws + 115220480, 0, 400000, stream);  // deg|cursor

    k_cvt_x<<<3125, 256, 0, stream>>>(x, xb);
    k_cvt_wt<<<64, 256, 0, stream>>>(W, Wt);
    k_wqk<<<RR, 128, 0, stream>>>(W, qw, kw, Wqkt);
    k_qk<<<391, 256, 0, stream>>>(xb, Wqkt, QT, KT);
    k_T<<<3126, 256, 0, stream>>>(xb, Wt, T);
    k_hist<<<(EE + 255) / 256, 256, 0, stream>>>(ei, deg);
    k_scan1<<<49, 1024, 0, stream>>>(deg, rowptr, bsum);
    k_scan2<<<1, 64, 0, stream>>>(bsum, boff);
    k_scan3<<<49, 1024, 0, stream>>>(rowptr, boff);
    k_scatter<<<(EE + 255) / 256, 256, 0, stream>>>(ei, et, rowptr, cursor, srow);
    k_attagg<<<NN, 64, 0, stream>>>(rowptr, srow, QT, KT, T, bias, out);
}

// Round 13
// 280.213 us; speedup vs baseline: 3.5821x; 1.1111x over previous
//
#include <hip/hip_runtime.h>

#define NN 50000
#define EE 800000
#define INC 128
#define HCC 128
#define RR 8
#define HH 4
#define CHUNK 256

typedef __attribute__((ext_vector_type(8))) short bf16x8;
typedef __attribute__((ext_vector_type(4))) float f32x4;

// ---------- helpers ----------
static __device__ __forceinline__ unsigned f2b_rne(float f) {
    unsigned u = __float_as_uint(f);
    return (u + 0x7FFFu + ((u >> 16) & 1u)) >> 16;
}
static __device__ __forceinline__ float b2f(unsigned short s) {
    return __uint_as_float(((unsigned)s) << 16);
}

// T-row channel permutation: channel ch=(2*mg2+half)*16+kq*4+reg stored at
// ushort pos = mg2*32 + kq*8 + half*4 + reg (verified R9).
// Wt swizzle: within each r-slice (128 rows x 16 chunks of 16B), chunk' =
// chunk ^ (row&15). k_T copies the slice linearly to LDS; ds_read_b128 of
// A-fragments (16 lanes reading 16 different rows at one chunk) then hits
// 16 distinct chunks -> spread across banks.

// ---------- prologue: x fp32 -> bf16 (row-major, feeds MFMA B-fragments) ----------
__global__ __launch_bounds__(256) void k_cvt_x(const float* __restrict__ x,
                                               unsigned short* __restrict__ xb) {
    int t = blockIdx.x * 256 + threadIdx.x;  // 800000 threads, 8 elems each
    const float4* p = (const float4*)x + t * 2;
    float4 v0 = p[0], v1 = p[1];
    uint4 pk;
    pk.x = f2b_rne(v0.x) | (f2b_rne(v0.y) << 16);
    pk.y = f2b_rne(v0.z) | (f2b_rne(v0.w) << 16);
    pk.z = f2b_rne(v1.x) | (f2b_rne(v1.y) << 16);
    pk.w = f2b_rne(v1.z) | (f2b_rne(v1.w) << 16);
    *((uint4*)xb + t) = pk;
}

// ---------- prologue: Wt_swz[r][row][chunk^row&15] = bf16(W[r][i][o]) ----------
__global__ __launch_bounds__(256) void k_cvt_wt(const float* __restrict__ W,
                                                unsigned short* __restrict__ Wts) {
    int t = blockIdx.x * 256 + threadIdx.x;  // 16384 threads
    int m = t & 127, kb = (t >> 7) & 15, r = t >> 11;  // row m, chunk kb
    unsigned short tmp[8];
#pragma unroll
    for (int j = 0; j < 8; ++j)
        tmp[j] = (unsigned short)f2b_rne(W[((r << 7) + (kb << 3) + j) * 128 + m]);
    uint4 pk;
    pk.x = tmp[0] | ((unsigned)tmp[1] << 16);
    pk.y = tmp[2] | ((unsigned)tmp[3] << 16);
    pk.z = tmp[4] | ((unsigned)tmp[5] << 16);
    pk.w = tmp[6] | ((unsigned)tmp[7] << 16);
    int idx = r * 2048 + m * 16 + (kb ^ (m & 15));  // uint4 index, swizzled
    *((uint4*)Wts + idx) = pk;
}

// ---------- K0: combined QK projection matrix, transposed bf16 ----------
__global__ __launch_bounds__(128) void k_wqk(const float* __restrict__ W,
                                             const float* __restrict__ qw,
                                             const float* __restrict__ kw,
                                             unsigned short* __restrict__ Wqkt) {
    int r = blockIdx.x, i = threadIdx.x;
    const float* wrow = W + (r * INC + i) * HCC;
    float aq0 = 0, aq1 = 0, aq2 = 0, aq3 = 0;
    float ak0 = 0, ak1 = 0, ak2 = 0, ak3 = 0;
    for (int o = 0; o < HCC; ++o) {
        float w = wrow[o];
        float4 qv = *(const float4*)(qw + o * 4);
        float4 kv = *(const float4*)(kw + o * 4);
        aq0 = fmaf(w, qv.x, aq0); aq1 = fmaf(w, qv.y, aq1);
        aq2 = fmaf(w, qv.z, aq2); aq3 = fmaf(w, qv.w, aq3);
        ak0 = fmaf(w, kv.x, ak0); ak1 = fmaf(w, kv.y, ak1);
        ak2 = fmaf(w, kv.z, ak2); ak3 = fmaf(w, kv.w, ak3);
    }
    int cq = r * 4, ck = 32 + r * 4;
    Wqkt[(cq + 0) * 128 + i] = (unsigned short)f2b_rne(aq0);
    Wqkt[(cq + 1) * 128 + i] = (unsigned short)f2b_rne(aq1);
    Wqkt[(cq + 2) * 128 + i] = (unsigned short)f2b_rne(aq2);
    Wqkt[(cq + 3) * 128 + i] = (unsigned short)f2b_rne(aq3);
    Wqkt[(ck + 0) * 128 + i] = (unsigned short)f2b_rne(ak0);
    Wqkt[(ck + 1) * 128 + i] = (unsigned short)f2b_rne(ak1);
    Wqkt[(ck + 2) * 128 + i] = (unsigned short)f2b_rne(ak2);
    Wqkt[(ck + 3) * 128 + i] = (unsigned short)f2b_rne(ak3);
}

// ---------- K1 (MFMA): [QT|KT] = x @ Wqk  (skinny GEMM, M=64 cols) ----------
__global__ __launch_bounds__(256, 4) void k_qk(const unsigned short* __restrict__ xb,
                                               const unsigned short* __restrict__ Wqkt,
                                               float* __restrict__ QT,
                                               float* __restrict__ KT) {
    int wave = (blockIdx.x * 256 + threadIdx.x) >> 6;  // 2 node-tiles per wave
    int lane = threadIdx.x & 63;
    int nt0 = wave * 2, nt1 = nt0 + 1;
    if (nt0 >= 3125) return;
    bool has1 = nt1 < 3125;
    int ln = lane & 15, kq = lane >> 4;

    const unsigned short* x0 = xb + (nt0 * 16 + ln) * 128 + kq * 8;
    const unsigned short* x1 = xb + ((has1 ? nt1 : nt0) * 16 + ln) * 128 + kq * 8;
    bf16x8 b0[4], b1[4];
#pragma unroll
    for (int ks = 0; ks < 4; ++ks) {
        b0[ks] = *(const bf16x8*)(x0 + ks * 32);
        b1[ks] = *(const bf16x8*)(x1 + ks * 32);
    }
    const unsigned short* ab = Wqkt + ln * 128 + kq * 8;
#pragma unroll
    for (int mg = 0; mg < 4; ++mg) {
        f32x4 acc0 = {0.f, 0.f, 0.f, 0.f};
        f32x4 acc1 = {0.f, 0.f, 0.f, 0.f};
#pragma unroll
        for (int ks = 0; ks < 4; ++ks) {
            bf16x8 a = *(const bf16x8*)(ab + mg * 2048 + ks * 32);
            acc0 = __builtin_amdgcn_mfma_f32_16x16x32_bf16(a, b0[ks], acc0, 0, 0, 0);
            acc1 = __builtin_amdgcn_mfma_f32_16x16x32_bf16(a, b1[ks], acc1, 0, 0, 0);
        }
        float* base = (mg < 2) ? QT : KT;
        int rr = (mg & 1) * 4 + kq;  // relation index
        *(f32x4*)(base + ((nt0 * 16 + ln) * 8 + rr) * 4) = acc0;
        if (has1) *(f32x4*)(base + ((nt1 * 16 + ln) * 8 + rr) * 4) = acc1;
    }
}

// ---------- K2 (MFMA): T = x @ W_r, W_r staged in LDS (swizzled) ----------
// Grid: 8 r x 196 tile-groups of 16 tiles. Block stages 32KB W_r once, then
// 4 waves x {2 groups x 2 tiles} compute. Cuts Wt L2/L3 reads 400MB -> 50MB.
__global__ __launch_bounds__(256) void k_T(const unsigned short* __restrict__ xb,
                                           const unsigned short* __restrict__ Wts,
                                           unsigned short* __restrict__ T) {
    __shared__ unsigned short lA[16384];  // 32KB, swizzled W_r slice
    const int r = blockIdx.x & 7;
    const int grp = blockIdx.x >> 3;  // 0..195
    const int tid = threadIdx.x;
    const int wv = tid >> 6, lane = tid & 63;
    const int ln = lane & 15, kq = lane >> 4;

    {   // stage: linear 32KB copy (source pre-swizzled by k_cvt_wt)
        const uint4* src = (const uint4*)Wts + r * 2048;
        uint4* dst = (uint4*)lA;
#pragma unroll
        for (int i = 0; i < 8; ++i) dst[i * 256 + tid] = src[i * 256 + tid];
    }
    __syncthreads();

#pragma unroll
    for (int g = 0; g < 2; ++g) {
        int nt0 = grp * 16 + g * 8 + wv * 2;
        int nt1 = nt0 + 1;
        bool h0 = nt0 < 3125, h1 = nt1 < 3125;
        int a0 = h0 ? nt0 : 3124, a1 = h1 ? nt1 : 3124;
        const unsigned short* x0 = xb + (a0 * 16 + ln) * 128 + kq * 8;
        const unsigned short* x1 = xb + (a1 * 16 + ln) * 128 + kq * 8;
        bf16x8 b0[4], b1[4];
#pragma unroll
        for (int ks = 0; ks < 4; ++ks) {
            b0[ks] = *(const bf16x8*)(x0 + ks * 32);
            b1[ks] = *(const bf16x8*)(x1 + ks * 32);
        }
#pragma unroll
        for (int mg2 = 0; mg2 < 4; ++mg2) {
            f32x4 e0 = {0.f, 0.f, 0.f, 0.f};
            f32x4 o0 = {0.f, 0.f, 0.f, 0.f};
            f32x4 e1 = {0.f, 0.f, 0.f, 0.f};
            f32x4 o1 = {0.f, 0.f, 0.f, 0.f};
            const int rowe = mg2 * 32 + ln;        // even mg = 2*mg2
            const int rowo = mg2 * 32 + 16 + ln;   // odd  mg
#pragma unroll
            for (int ks = 0; ks < 4; ++ks) {
                int ch = (kq + ks * 4) ^ ln;  // swizzled chunk
                bf16x8 ae = *(const bf16x8*)(lA + rowe * 128 + ch * 8);
                bf16x8 ao = *(const bf16x8*)(lA + rowo * 128 + ch * 8);
                e0 = __builtin_amdgcn_mfma_f32_16x16x32_bf16(ae, b0[ks], e0, 0, 0, 0);
                o0 = __builtin_amdgcn_mfma_f32_16x16x32_bf16(ao, b0[ks], o0, 0, 0, 0);
                e1 = __builtin_amdgcn_mfma_f32_16x16x32_bf16(ae, b1[ks], e1, 0, 0, 0);
                o1 = __builtin_amdgcn_mfma_f32_16x16x32_bf16(ao, b1[ks], o1, 0, 0, 0);
            }
            uint4 pk0, pk1;
            pk0.x = f2b_rne(e0[0]) | (f2b_rne(e0[1]) << 16);
            pk0.y = f2b_rne(e0[2]) | (f2b_rne(e0[3]) << 16);
            pk0.z = f2b_rne(o0[0]) | (f2b_rne(o0[1]) << 16);
            pk0.w = f2b_rne(o0[2]) | (f2b_rne(o0[3]) << 16);
            pk1.x = f2b_rne(e1[0]) | (f2b_rne(e1[1]) << 16);
            pk1.y = f2b_rne(e1[2]) | (f2b_rne(e1[3]) << 16);
            pk1.z = f2b_rne(o1[0]) | (f2b_rne(o1[1]) << 16);
            pk1.w = f2b_rne(o1[2]) | (f2b_rne(o1[3]) << 16);
            int pos = mg2 * 32 + kq * 8;  // ushort offset in permuted row
            if (h0) *(uint4*)(T + ((nt0 * 16 + ln) * 8 + r) * 128 + pos) = pk0;
            if (h1) *(uint4*)(T + ((nt1 * 16 + ln) * 8 + r) * 128 + pos) = pk1;
        }
    }
}

// ---------- CSR build ----------
__global__ __launch_bounds__(256) void k_hist(const int* __restrict__ ei,
                                              int* __restrict__ deg) {
    int e = blockIdx.x * 256 + threadIdx.x;
    if (e >= EE) return;
    atomicAdd(&deg[ei[EE + e]], 1);
}

__global__ __launch_bounds__(1024) void k_scan1(const int* __restrict__ deg,
                                                int* __restrict__ rowptr,
                                                int* __restrict__ bsum) {
    __shared__ int s[1024];
    int tid = threadIdx.x;
    int g = blockIdx.x * 1024 + tid;
    int v = (g < NN) ? deg[g] : 0;
    s[tid] = v;
    __syncthreads();
    for (int off = 1; off < 1024; off <<= 1) {
        int t = (tid >= off) ? s[tid - off] : 0;
        __syncthreads();
        s[tid] += t;
        __syncthreads();
    }
    if (g < NN) rowptr[g + 1] = s[tid];  // chunk-local inclusive
    if (tid == 1023) bsum[blockIdx.x] = s[1023];
}

__global__ void k_scan2(const int* __restrict__ bsum, int* __restrict__ boff) {
    int tid = threadIdx.x;  // 64 = 1 wave
    const int NB = (NN + 1023) / 1024;  // 49
    int v = (tid < NB) ? bsum[tid] : 0;
    int orig = v;
    for (int off = 1; off < 64; off <<= 1) {
        int t = __shfl_up(v, off);
        if (tid >= off) v += t;
    }
    if (tid < NB) boff[tid] = v - orig;  // exclusive
}

__global__ __launch_bounds__(1024) void k_scan3(int* __restrict__ rowptr,
                                                const int* __restrict__ boff) {
    int tid = threadIdx.x;
    int g = blockIdx.x * 1024 + tid;
    if (g == 0) rowptr[0] = 0;
    if (g < NN) rowptr[g + 1] += boff[blockIdx.x];
}

__global__ __launch_bounds__(256) void k_scatter(const int* __restrict__ ei,
                                                 const int* __restrict__ et,
                                                 const int* __restrict__ rowptr,
                                                 int* __restrict__ cursor,
                                                 unsigned* __restrict__ srow) {
    int e = blockIdx.x * 256 + threadIdx.x;
    if (e >= EE) return;
    int src = ei[e], dst = ei[EE + e], r = et[e];
    int pos = rowptr[dst] + atomicAdd(&cursor[dst], 1);
    srow[pos] = (unsigned)(src * RR + r);  // T row index (src*8+r)
}

// ---------- fused attention + aggregate: one wave per node, flash-style ----------
__global__ __launch_bounds__(64) void k_attagg(const int* __restrict__ rowptr,
                                               const unsigned* __restrict__ srow,
                                               const float* __restrict__ QT,
                                               const float* __restrict__ KT,
                                               const unsigned short* __restrict__ T,
                                               const float* __restrict__ bias,
                                               float* __restrict__ out) {
    __shared__ float als[CHUNK * 4];
    __shared__ unsigned srw[CHUNK];
    __shared__ float qs[32];
    const int n = blockIdx.x;
    const int lane = threadIdx.x;
    const int h = lane >> 4;       // head for channels 2*lane, 2*lane+1
    const int c = lane * 2;
    // permuted T-row offset for channel pair (c, c+1)
    const int mgv = c >> 4, kqv = (c >> 2) & 3, regv = c & 3;
    const int posu = (mgv >> 1) * 32 + kqv * 8 + (mgv & 1) * 4 + regv;
    const int beg = rowptr[n], end = rowptr[n + 1];

    if (lane < 32) qs[lane] = QT[n * 32 + lane];
    __syncthreads();

    float m0 = -3.0e38f, m1 = -3.0e38f, m2 = -3.0e38f, m3 = -3.0e38f;
    float d0 = 0.f, d1 = 0.f, d2 = 0.f, d3 = 0.f;
    float accx = 0.f, accy = 0.f;

    for (int j0 = beg; j0 < end; j0 += CHUNK) {
        const int cnt = min(CHUNK, end - j0);
        // --- phase A: edge-parallel logits + local max ---
        float lm0 = -3.0e38f, lm1 = -3.0e38f, lm2 = -3.0e38f, lm3 = -3.0e38f;
        for (int jj = lane; jj < cnt; jj += 64) {
            unsigned sr = srow[j0 + jj];
            srw[jj] = sr;
            int r = sr & 7;
            float4 kj = *(const float4*)(KT + sr * 4);
            float a0 = qs[r * 4 + 0] + kj.x;
            float a1 = qs[r * 4 + 1] + kj.y;
            float a2 = qs[r * 4 + 2] + kj.z;
            float a3 = qs[r * 4 + 3] + kj.w;
            a0 = a0 > 0.f ? a0 : 0.2f * a0;
            a1 = a1 > 0.f ? a1 : 0.2f * a1;
            a2 = a2 > 0.f ? a2 : 0.2f * a2;
            a3 = a3 > 0.f ? a3 : 0.2f * a3;
            als[jj * 4 + 0] = a0; als[jj * 4 + 1] = a1;
            als[jj * 4 + 2] = a2; als[jj * 4 + 3] = a3;
            lm0 = fmaxf(lm0, a0); lm1 = fmaxf(lm1, a1);
            lm2 = fmaxf(lm2, a2); lm3 = fmaxf(lm3, a3);
        }
        __syncthreads();
        // --- wave max reduce ---
#pragma unroll
        for (int off = 1; off < 64; off <<= 1) {
            lm0 = fmaxf(lm0, __shfl_xor(lm0, off));
            lm1 = fmaxf(lm1, __shfl_xor(lm1, off));
            lm2 = fmaxf(lm2, __shfl_xor(lm2, off));
            lm3 = fmaxf(lm3, __shfl_xor(lm3, off));
        }
        // --- online rescale ---
        float nm0 = fmaxf(m0, lm0), nm1 = fmaxf(m1, lm1);
        float nm2 = fmaxf(m2, lm2), nm3 = fmaxf(m3, lm3);
        float s0 = expf(m0 - nm0), s1 = expf(m1 - nm1);
        float s2 = expf(m2 - nm2), s3 = expf(m3 - nm3);
        d0 *= s0; d1 *= s1; d2 *= s2; d3 *= s3;
        float sh = h == 0 ? s0 : h == 1 ? s1 : h == 2 ? s2 : s3;
        accx *= sh; accy *= sh;
        m0 = nm0; m1 = nm1; m2 = nm2; m3 = nm3;
        // --- phase D: exp + denom partial ---
        float p0 = 0.f, p1 = 0.f, p2 = 0.f, p3 = 0.f;
        for (int jj = lane; jj < cnt; jj += 64) {
            float e0 = expf(als[jj * 4 + 0] - m0);
            float e1 = expf(als[jj * 4 + 1] - m1);
            float e2 = expf(als[jj * 4 + 2] - m2);
            float e3 = expf(als[jj * 4 + 3] - m3);
            als[jj * 4 + 0] = e0; als[jj * 4 + 1] = e1;
            als[jj * 4 + 2] = e2; als[jj * 4 + 3] = e3;
            p0 += e0; p1 += e1; p2 += e2; p3 += e3;
        }
#pragma unroll
        for (int off = 1; off < 64; off <<= 1) {
            p0 += __shfl_xor(p0, off);
            p1 += __shfl_xor(p1, off);
            p2 += __shfl_xor(p2, off);
            p3 += __shfl_xor(p3, off);
        }
        d0 += p0; d1 += p1; d2 += p2; d3 += p3;
        __syncthreads();
        // --- phase E: channel-parallel weighted T accumulate (permuted read) ---
        for (int jj = 0; jj < cnt; ++jj) {
            float w = als[jj * 4 + h];
            unsigned pk = *(const unsigned*)(T + srw[jj] * 128 + posu);
            accx = fmaf(w, b2f((unsigned short)(pk & 0xFFFF)), accx);
            accy = fmaf(w, b2f((unsigned short)(pk >> 16)), accy);
        }
        __syncthreads();
    }
    float dh = h == 0 ? d0 : h == 1 ? d1 : h == 2 ? d2 : d3;
    float inv = 1.f / (dh + 1e-16f);
    out[n * 128 + c] = accx * inv + bias[c];
    out[n * 128 + c + 1] = accy * inv + bias[c + 1];
}

extern "C" void kernel_launch(void* const* d_in, const int* in_sizes, int n_in,
                              void* d_out, int out_size, void* d_ws, size_t ws_size,
                              hipStream_t stream) {
    const float* x    = (const float*)d_in[0];
    const int*   ei   = (const int*)d_in[1];
    const int*   et   = (const int*)d_in[2];
    const float* W    = (const float*)d_in[3];
    const float* qw   = (const float*)d_in[4];
    const float* kw   = (const float*)d_in[5];
    const float* bias = (const float*)d_in[6];
    float* out = (float*)d_out;
    char* ws = (char*)d_ws;

    // workspace layout (bytes) — total ~132 MB
    unsigned short* T    = (unsigned short*)(ws + 0);          // 102,400,000
    float* QT            = (float*)(ws + 102400000);           //   6,400,000
    float* KT            = (float*)(ws + 108800000);           //   6,400,000
    unsigned short* Wqkt = (unsigned short*)(ws + 115200000);  //      16,384
    int* deg             = (int*)(ws + 115220480);             //     200,000 (zeroed)
    int* cursor          = (int*)(ws + 115420480);             //     200,000 (zeroed)
    int* rowptr          = (int*)(ws + 115620480);             //     200,004
    int* bsum            = (int*)(ws + 115820484);             //         256
    int* boff            = (int*)(ws + 115820740);             //         256
    unsigned* srow       = (unsigned*)(ws + 115820996);        //   3,200,000
    // transient (dead after k_T/k_qk):
    unsigned short* xb   = (unsigned short*)(ws + 119021056);  //  12,800,000 (16B-aligned)
    unsigned short* Wts  = (unsigned short*)(ws + 131821056);  //     262,144 (swizzled)

    hipMemsetAsync(ws + 115220480, 0, 400000, stream);  // deg|cursor

    k_cvt_x<<<3125, 256, 0, stream>>>(x, xb);
    k_cvt_wt<<<64, 256, 0, stream>>>(W, Wts);
    k_wqk<<<RR, 128, 0, stream>>>(W, qw, kw, Wqkt);
    k_qk<<<391, 256, 0, stream>>>(xb, Wqkt, QT, KT);
    k_T<<<8 * 196, 256, 0, stream>>>(xb, Wts, T);
    k_hist<<<(EE + 255) / 256, 256, 0, stream>>>(ei, deg);
    k_scan1<<<49, 1024, 0, stream>>>(deg, rowptr, bsum);
    k_scan2<<<1, 64, 0, stream>>>(bsum, boff);
    k_scan3<<<49, 1024, 0, stream>>>(rowptr, boff);
    k_scatter<<<(EE + 255) / 256, 256, 0, stream>>>(ei, et, rowptr, cursor, srow);
    k_attagg<<<NN, 64, 0, stream>>>(rowptr, srow, QT, KT, T, bias, out);
}